// Round 8
// baseline (247.965 us; speedup 1.0000x reference)
//
#include <hip/hip_runtime.h>
#include <hip/hip_bf16.h>

#define N_NODES 100000
#define N_EDGES 3200000
#define NB ((N_NODES + 255) / 256)   // 391
#define NBUCKET NB                   // coarse bucket = dst>>8
#define EPB 8192                     // edges per k_pass1 block
#define NPB ((N_EDGES + EPB - 1) / EPB)  // 391 blocks
#define BCAP 11264                   // per-bucket cap incl self+pad(8)+guard; mean ~9344, 20 sigma
#define GCS 16                       // gcur stride (ints): 1 counter per 64-B line

typedef short short8 __attribute__((ext_vector_type(8)));
typedef float f32x4 __attribute__((ext_vector_type(4)));

// RNE float->bf16 bits (matches __float2bfloat16 for finite values)
__device__ inline unsigned f2bf(float f) {
  unsigned x = __float_as_uint(f);
  return (x + 0x7FFFu + ((x >> 16) & 1u)) >> 16;
}

// ---------------- pass 1: register-resident coarse partition ----------------
// item: bits[16:0] = src, bits[24:17] = dst & 255 (bucket = dst>>8).
// Single LDS-atomic round: per-item position packed into bits[31:25].

__global__ void __launch_bounds__(256) k_pass1(const int* __restrict__ src,
                                               const int* __restrict__ dst,
                                               int* __restrict__ gcur,
                                               unsigned int* __restrict__ eb) {
  __shared__ int hist[NBUCKET];
  __shared__ int gbase[NBUCKET];
  int tid = threadIdx.x;
  int base = blockIdx.x * EPB;
  int cnt = min(EPB, N_EDGES - base);   // multiple of 4
  int n4 = cnt >> 2;
  for (int i = tid; i < NBUCKET; i += 256) hist[i] = 0;
  __syncthreads();
  const int4* d4 = (const int4*)(dst + base);
  const int4* s4 = (const int4*)(src + base);
  unsigned mv[32];
  unsigned short mb[32];
#pragma unroll
  for (int k = 0; k < 8; ++k) {
    int i = tid + (k << 8);
    if (i < n4) {
      int4 dv = d4[i];
      int4 sv = s4[i];
      int b0 = dv.x >> 8, b1_ = dv.y >> 8, b2 = dv.z >> 8, b3 = dv.w >> 8;
      unsigned p0 = atomicAdd(&hist[b0], 1);
      unsigned p1 = atomicAdd(&hist[b1_], 1);
      unsigned p2 = atomicAdd(&hist[b2], 1);
      unsigned p3 = atomicAdd(&hist[b3], 1);
      mv[4 * k + 0] = (unsigned)sv.x | ((unsigned)(dv.x & 255) << 17) | (p0 << 25);
      mv[4 * k + 1] = (unsigned)sv.y | ((unsigned)(dv.y & 255) << 17) | (p1 << 25);
      mv[4 * k + 2] = (unsigned)sv.z | ((unsigned)(dv.z & 255) << 17) | (p2 << 25);
      mv[4 * k + 3] = (unsigned)sv.w | ((unsigned)(dv.w & 255) << 17) | (p3 << 25);
      mb[4 * k + 0] = (unsigned short)b0;
      mb[4 * k + 1] = (unsigned short)b1_;
      mb[4 * k + 2] = (unsigned short)b2;
      mb[4 * k + 3] = (unsigned short)b3;
    } else {
      mb[4 * k + 0] = 0xFFFF; mb[4 * k + 1] = 0xFFFF;
      mb[4 * k + 2] = 0xFFFF; mb[4 * k + 3] = 0xFFFF;
    }
  }
  __syncthreads();
  for (int b = tid; b < NBUCKET; b += 256) {
    int h = hist[b];
    gbase[b] = h ? atomicAdd(&gcur[b * GCS], h) : 0;  // one claim per (block,bucket)
  }
  __syncthreads();
#pragma unroll
  for (int k = 0; k < 32; ++k) {
    if (mb[k] != 0xFFFF) {
      int b = mb[k];
      unsigned v = mv[k];
      unsigned pos = (unsigned)gbase[b] + (v >> 25);
      if (pos < BCAP) eb[(size_t)b * BCAP + pos] = v & 0x01FFFFFFu;
    }
  }
}

// ---------------- pass 2: per-bucket counting sort + self-edge + pad-to-8 --------
// Node n's run: [rs[n], re[n]) real (self first), pads == N_NODES to a multiple
// of 8, 16-entry guard after the bucket total. Also emits dis, xd = x4*dis.
// Scan over 256 threads = wave shfl_up scan + 4-entry cross-wave combine.

__global__ void __launch_bounds__(256) k_part2(unsigned int* __restrict__ eb,
                                               const int* __restrict__ gcur,
                                               int* __restrict__ rs, int* __restrict__ re,
                                               float* __restrict__ dis,
                                               const float4* __restrict__ x4,
                                               float4* __restrict__ xd) {
  __shared__ int hist[256], scn[256], cur[256];
  __shared__ int wsum[4];
  __shared__ int tot;
  __shared__ unsigned int stage[BCAP];
  int b = blockIdx.x, tid = threadIdx.x;
  int lane = tid & 63, wid = tid >> 6;
  int n0 = b << 8;
  int cnt = gcur[b * GCS];
  int base = b * BCAP;
  hist[tid] = 0; cur[tid] = 0;
  __syncthreads();
  for (int i = tid; i < cnt; i += 256)
    atomicAdd(&hist[eb[base + i] >> 17], 1);
  __syncthreads();
  int n = n0 + tid;
  int deg = hist[tid];
  int slots = (n < N_NODES) ? ((deg + 1 + 7) & ~7) : 0;
  // inclusive scan of slots: shfl_up within wave, then cross-wave offsets
  int v = slots;
#pragma unroll
  for (int off = 1; off < 64; off <<= 1) {
    int t = __shfl_up(v, off);
    if (lane >= off) v += t;
  }
  if (lane == 63) wsum[wid] = v;
  __syncthreads();
  int x = v;
#pragma unroll
  for (int w2 = 0; w2 < 3; ++w2)
    if (wid > w2) x += wsum[w2];
  int excl = x - slots;
  if (tid == 255) tot = x;
  if (n < N_NODES) {
    rs[n]  = base + excl;
    re[n]  = base + excl + deg + 1;
    float dn = rsqrtf((float)(deg + 1));
    dis[n] = dn;
    float4 xv = x4[n];
    float4 w; w.x = xv.x * dn; w.y = xv.y * dn; w.z = xv.z * dn; w.w = xv.w * dn;
    xd[n] = w;
    stage[excl] = (unsigned)n;                    // self edge
    for (int i = deg + 1; i < slots; ++i)
      stage[excl + i] = (unsigned)N_NODES;        // zero-row pads
  }
  if (b == 0 && tid == 0) xd[N_NODES] = make_float4(0.f, 0.f, 0.f, 0.f);
  scn[tid] = excl + 1;                            // in-edge start
  __syncthreads();
  for (int i = tid; i < cnt; i += 256) {
    unsigned v2 = eb[base + i];
    unsigned low = v2 >> 17;
    int lpos = scn[low] + atomicAdd(&cur[low], 1);
    stage[lpos] = v2 & 0x1FFFFu;
  }
  __syncthreads();
  int total = tot;
  for (int i = tid; i < total; i += 256)
    eb[base + i] = stage[i];     // eb is now padded CSR (src ids by dst node)
  if (tid < 16) {                // guard pads for k_agg's prefetch over-read
    int gp = total + tid;
    if (gp < BCAP) eb[base + gp] = (unsigned)N_NODES;
  }
}

// ---------------- Layer 1 fused: aggregate xd + transform + bf16 store ----------
// 4 threads per node (p = gt&3). Thread p reads csr dwords e0+4t+p (slots are
// multiples of 8; pads hit xd's zero row), shfl_xor combine, then writes
// feature slice [16p, 16p+16) of h1s[n] = bf16(relu(b1 + agg·W1) * dis[n]).

__global__ void __launch_bounds__(256) k_l1(const float4* __restrict__ xd,
                                            const float* __restrict__ dis,
                                            const int* __restrict__ rs,
                                            const int* __restrict__ re,
                                            const int* __restrict__ csr,
                                            const float* __restrict__ W1,
                                            const float* __restrict__ b1,
                                            unsigned int* __restrict__ h1o) {
  int gt = blockIdx.x * 256 + threadIdx.x;
  int nid = gt >> 2, p = gt & 3;
  if (nid > N_NODES) return;
  if (nid == N_NODES) {                       // zero row (pad target for k_agg)
    uint4 z = make_uint4(0u, 0u, 0u, 0u);
    uint4* op = (uint4*)(h1o + nid * 32 + p * 8);
    op[0] = z; op[1] = z;
    return;
  }
  int e0 = rs[nid];
  int it4 = ((re[nid] - e0 + 7) & ~7) >> 2;   // dword quads per thread-pass
  const int* cp = csr + e0 + p;
  float ax = 0.f, ay = 0.f, az = 0.f, aw = 0.f;
#pragma unroll 4
  for (int t = 0; t < it4; ++t) {
    int s = cp[t << 2];
    float4 v = xd[s];
    ax += v.x; ay += v.y; az += v.z; aw += v.w;
  }
  ax += __shfl_xor(ax, 1); ax += __shfl_xor(ax, 2);
  ay += __shfl_xor(ay, 1); ay += __shfl_xor(ay, 2);
  az += __shfl_xor(az, 1); az += __shfl_xor(az, 2);
  aw += __shfl_xor(aw, 1); aw += __shfl_xor(aw, 2);
  float dn = dis[nid];
  ax *= dn; ay *= dn; az *= dn; aw *= dn;     // agg1[nid]
  int j0 = p << 4;
  unsigned ou[8];
#pragma unroll
  for (int j2 = 0; j2 < 8; ++j2) {
    int j = j0 + j2 * 2;
    float s0 = b1[j]     + ax * W1[j]     + ay * W1[64 + j]     + az * W1[128 + j]     + aw * W1[192 + j];
    float s1 = b1[j + 1] + ax * W1[j + 1] + ay * W1[64 + j + 1] + az * W1[128 + j + 1] + aw * W1[192 + j + 1];
    unsigned u0 = f2bf(fmaxf(s0, 0.f) * dn);
    unsigned u1 = f2bf(fmaxf(s1, 0.f) * dn);
    ou[j2] = u0 | (u1 << 16);
  }
  uint4* op = (uint4*)(h1o + nid * 32 + p * 8);
  op[0] = make_uint4(ou[0], ou[1], ou[2], ou[3]);
  op[1] = make_uint4(ou[4], ou[5], ou[6], ou[7]);
}

// ---------------- Layer-2 fused: gather + MFMA GEMV + out ----------------------
// Block = 1024 threads = 16 waves = 16 nodes (N = 6250*16 exactly). Wave wid
// aggregates node n = blk*16+wid (2-deep pipelined gather, r1-proven), packs its
// bf16 agg row into LDS arow[wid]. After the barrier, wave 0 runs the 16-node
// MFMA tile (R6 k_final body, A-fragments from LDS) and stores out directly.
// Kills the k_final dispatch (+graph gap) and the 25.6 MB aggb round-trip.
// arow padded to 72 shorts/row: wave0's ds_read_b128 pattern (m*144 + kg*16 B)
// then covers all banks uniformly (8 dwords/bank = structural minimum).

__device__ inline void acc_bf2(float& a0, float& a1, unsigned u) {
  a0 += __uint_as_float(u << 16);
  a1 += __uint_as_float(u & 0xffff0000u);
}

__global__ void __launch_bounds__(1024)
k_agg(const __hip_bfloat16* __restrict__ h1s, const float* __restrict__ dis,
      const int* __restrict__ rs, const int* __restrict__ re,
      const int* __restrict__ csr,
      const float* __restrict__ W2, const float* __restrict__ b2,
      const float* __restrict__ Wf, const float* __restrict__ bf,
      float* __restrict__ out) {
  __shared__ unsigned short arow[16][72];     // 16 agg rows, +8 pad shorts
  int l = threadIdx.x & 63;
  int wid = threadIdx.x >> 6;                 // 0..15
  int n = blockIdx.x * 16 + wid;
  int g = l >> 3;
  int c = l & 7;

  const unsigned int* h32 = (const unsigned int*)h1s;
  int e0 = rs[n];
  int iter = (re[n] - e0 + 7) >> 3;           // padded 8-blocks, >= 1
  const int* cb = csr + e0 + g;
  int coff = c << 2;                          // dword offset of feature chunk

  float a0 = 0.f, a1 = 0.f, a2 = 0.f, a3 = 0.f;
  float a4 = 0.f, a5 = 0.f, a6 = 0.f, a7 = 0.f;
  int sc = cb[0];                             // iter 0 edge id
  int sn = cb[8];                             // iter 1 (guard-safe)
  uint4 u = *(const uint4*)(h32 + (sc << 5) + coff);
  for (int it = 1; it < iter; ++it) {
    int sf = cb[(it + 1) << 3];               // 2-ahead csr (guard-safe)
    uint4 r = *(const uint4*)(h32 + (sn << 5) + coff);
    acc_bf2(a0, a1, u.x); acc_bf2(a2, a3, u.y);
    acc_bf2(a4, a5, u.z); acc_bf2(a6, a7, u.w);
    u = r; sn = sf;
  }
  acc_bf2(a0, a1, u.x); acc_bf2(a2, a3, u.y);
  acc_bf2(a4, a5, u.z); acc_bf2(a6, a7, u.w);

  // reduce across the 8 edge-subgroups (lane bits 3,4,5)
#define RED3(a) a += __shfl_xor(a, 8); a += __shfl_xor(a, 16); a += __shfl_xor(a, 32);
  RED3(a0) RED3(a1) RED3(a2) RED3(a3) RED3(a4) RED3(a5) RED3(a6) RED3(a7)
#undef RED3

  float dn = dis[n];
  if (l < 8) {                                // lane l == chunk c: feats 8l..8l+7
    unsigned q0 = f2bf(a0 * dn) | (f2bf(a1 * dn) << 16);
    unsigned q1 = f2bf(a2 * dn) | (f2bf(a3 * dn) << 16);
    unsigned q2 = f2bf(a4 * dn) | (f2bf(a5 * dn) << 16);
    unsigned q3 = f2bf(a6 * dn) | (f2bf(a7 * dn) << 16);
    *(uint4*)&arow[wid][l << 3] = make_uint4(q0, q1, q2, q3);   // 16-B aligned (144*wid+16*l)
  }
  __syncthreads();
  if (wid != 0) return;

  // ---- wave 0: MFMA tile for the block's 16 nodes (R6 k_final body) ----
  int n0 = blockIdx.x * 16;
  int m = l & 15;
  int kg = l >> 4;                            // 0..3

  // B fragments: W2[k][n], k = kt*32 + kg*8 + j, n = nt*16 + m
  short8 bfr[2][4];
#pragma unroll
  for (int kt = 0; kt < 2; ++kt) {
#pragma unroll
    for (int nt = 0; nt < 4; ++nt) {
      short8 t;
#pragma unroll
      for (int j = 0; j < 8; ++j) {
        int k = kt * 32 + kg * 8 + j;
        t[j] = (short)f2bf(W2[k * 64 + nt * 16 + m]);
      }
      bfr[kt][nt] = t;
    }
  }
  // A fragments from LDS: row m, k = kg*8 + j (+32 for kt=1)
  const unsigned short* ar = &arow[m][kg << 3];
  short8 af0 = *(const short8*)(ar);
  short8 af1 = *(const short8*)(ar + 32);

  f32x4 z = {0.f, 0.f, 0.f, 0.f};
  f32x4 acc0 = z, acc1 = z, acc2 = z, acc3 = z;
  acc0 = __builtin_amdgcn_mfma_f32_16x16x32_bf16(af0, bfr[0][0], acc0, 0, 0, 0);
  acc1 = __builtin_amdgcn_mfma_f32_16x16x32_bf16(af0, bfr[0][1], acc1, 0, 0, 0);
  acc2 = __builtin_amdgcn_mfma_f32_16x16x32_bf16(af0, bfr[0][2], acc2, 0, 0, 0);
  acc3 = __builtin_amdgcn_mfma_f32_16x16x32_bf16(af0, bfr[0][3], acc3, 0, 0, 0);
  acc0 = __builtin_amdgcn_mfma_f32_16x16x32_bf16(af1, bfr[1][0], acc0, 0, 0, 0);
  acc1 = __builtin_amdgcn_mfma_f32_16x16x32_bf16(af1, bfr[1][1], acc1, 0, 0, 0);
  acc2 = __builtin_amdgcn_mfma_f32_16x16x32_bf16(af1, bfr[1][2], acc2, 0, 0, 0);
  acc3 = __builtin_amdgcn_mfma_f32_16x16x32_bf16(af1, bfr[1][3], acc3, 0, 0, 0);

  // epilogue: for each nt, col = nt*16+m; rows kg*4+r
  float p0[4] = {0.f, 0.f, 0.f, 0.f};
  float p1[4] = {0.f, 0.f, 0.f, 0.f};
#pragma unroll
  for (int nt = 0; nt < 4; ++nt) {
    int col = nt * 16 + m;
    float bb = b2[col];
    float w0 = Wf[col * 2 + 0];
    float w1 = Wf[col * 2 + 1];
    f32x4 av = (nt == 0) ? acc0 : (nt == 1) ? acc1 : (nt == 2) ? acc2 : acc3;
#pragma unroll
    for (int r = 0; r < 4; ++r) {
      float tv = fmaxf(av[r] + bb, 0.f);
      p0[r] = fmaf(tv, w0, p0[r]);
      p1[r] = fmaf(tv, w1, p1[r]);
    }
  }
  // reduce across the 16 columns (lane bits 0..3)
#pragma unroll
  for (int r = 0; r < 4; ++r) {
    p0[r] += __shfl_xor(p0[r], 1); p0[r] += __shfl_xor(p0[r], 2);
    p0[r] += __shfl_xor(p0[r], 4); p0[r] += __shfl_xor(p0[r], 8);
    p1[r] += __shfl_xor(p1[r], 1); p1[r] += __shfl_xor(p1[r], 2);
    p1[r] += __shfl_xor(p1[r], 4); p1[r] += __shfl_xor(p1[r], 8);
  }
  float bf0 = bf[0], bf1 = bf[1];
  int rowb = n0 + kg * 4;
  if (m == 0) *(float2*)(out + (rowb + 0) * 2) = make_float2(p0[0] + bf0, p1[0] + bf1);
  if (m == 1) *(float2*)(out + (rowb + 1) * 2) = make_float2(p0[1] + bf0, p1[1] + bf1);
  if (m == 2) *(float2*)(out + (rowb + 2) * 2) = make_float2(p0[2] + bf0, p1[2] + bf1);
  if (m == 3) *(float2*)(out + (rowb + 3) * 2) = make_float2(p0[3] + bf0, p1[3] + bf1);
}

// ---------------- launch ----------------

extern "C" void kernel_launch(void* const* d_in, const int* in_sizes, int n_in,
                              void* d_out, int out_size, void* d_ws, size_t ws_size,
                              hipStream_t stream) {
  const float* x  = (const float*)d_in[0];
  const int*   ei = (const int*)d_in[1];     // [2, E] row-major, int32
  const float* W1 = (const float*)d_in[2];
  const float* b1 = (const float*)d_in[3];
  const float* W2 = (const float*)d_in[4];
  const float* b2 = (const float*)d_in[5];
  const float* Wf = (const float*)d_in[6];
  const float* bf = (const float*)d_in[7];
  float* out = (float*)d_out;

  const int* srcv = ei;
  const int* dstv = ei + N_EDGES;

  char* p = (char*)d_ws;
  auto take = [&](size_t bytes) { char* r = p; p += (bytes + 255) & ~(size_t)255; return r; };
  int*          gcur = (int*)take((size_t)NBUCKET * GCS * 4);                   // 64-B strided counters
  unsigned int* eb   = (unsigned int*)take((size_t)NBUCKET * BCAP * 4 + 512);  // padded CSR
  int*          rs   = (int*)take((size_t)N_NODES * 4);
  int*          re   = (int*)take((size_t)N_NODES * 4);
  float*        dis  = (float*)take((size_t)N_NODES * 4);
  float4*       xd   = (float4*)take((size_t)(N_NODES + 1) * 16);               // + zero row
  __hip_bfloat16* h1s = (__hip_bfloat16*)take((size_t)(N_NODES + 1) * 64 * 2);  // + zero row

  (void)hipMemsetAsync(gcur, 0, (size_t)NBUCKET * GCS * 4, stream);
  k_pass1<<<NPB, 256, 0, stream>>>(srcv, dstv, gcur, eb);
  k_part2<<<NBUCKET, 256, 0, stream>>>(eb, gcur, rs, re, dis, (const float4*)x, xd);
  const int* csr = (const int*)eb;
  k_l1<<<((N_NODES + 1) * 4 + 255) / 256, 256, 0, stream>>>(xd, dis, rs, re, csr, W1, b1, (unsigned int*)h1s);
  k_agg<<<N_NODES / 16, 1024, 0, stream>>>(h1s, dis, rs, re, csr, W2, b2, Wf, bf, out);
}

// Round 9
// 216.227 us; speedup vs baseline: 1.1468x; 1.1468x over previous
//
#include <hip/hip_runtime.h>
#include <hip/hip_bf16.h>

#define N_NODES 100000
#define N_EDGES 3200000
#define NB ((N_NODES + 255) / 256)   // 391
#define NBUCKET NB                   // coarse bucket = dst>>8
#define EPB 8192                     // edges per k_pass1 block
#define NPB ((N_EDGES + EPB - 1) / EPB)  // 391 blocks
#define BCAP 11264                   // per-bucket cap incl self+pad(8)+guard; mean ~9344, 20 sigma
#define KF_TILES (N_NODES / 16)      // 6250 MFMA tiles (16 nodes each), exact
#define KF_BLOCKS ((KF_TILES + 3) / 4)  // 1563 blocks of 4 waves
#define GCS 16                       // gcur stride (ints): 1 counter per 64-B line

typedef short short8 __attribute__((ext_vector_type(8)));
typedef float f32x4 __attribute__((ext_vector_type(4)));

// RNE float->bf16 bits (matches __float2bfloat16 for finite values)
__device__ inline unsigned f2bf(float f) {
  unsigned x = __float_as_uint(f);
  return (x + 0x7FFFu + ((x >> 16) & 1u)) >> 16;
}

// ---------------- pass 1: register-resident coarse partition ----------------
// item: bits[16:0] = src, bits[24:17] = dst & 255 (bucket = dst>>8).
// Single LDS-atomic round: per-item position packed into bits[31:25].

__global__ void __launch_bounds__(256) k_pass1(const int* __restrict__ src,
                                               const int* __restrict__ dst,
                                               int* __restrict__ gcur,
                                               unsigned int* __restrict__ eb) {
  __shared__ int hist[NBUCKET];
  __shared__ int gbase[NBUCKET];
  int tid = threadIdx.x;
  int base = blockIdx.x * EPB;
  int cnt = min(EPB, N_EDGES - base);   // multiple of 4
  int n4 = cnt >> 2;
  for (int i = tid; i < NBUCKET; i += 256) hist[i] = 0;
  __syncthreads();
  const int4* d4 = (const int4*)(dst + base);
  const int4* s4 = (const int4*)(src + base);
  unsigned mv[32];
  unsigned short mb[32];
#pragma unroll
  for (int k = 0; k < 8; ++k) {
    int i = tid + (k << 8);
    if (i < n4) {
      int4 dv = d4[i];
      int4 sv = s4[i];
      int b0 = dv.x >> 8, b1_ = dv.y >> 8, b2 = dv.z >> 8, b3 = dv.w >> 8;
      unsigned p0 = atomicAdd(&hist[b0], 1);
      unsigned p1 = atomicAdd(&hist[b1_], 1);
      unsigned p2 = atomicAdd(&hist[b2], 1);
      unsigned p3 = atomicAdd(&hist[b3], 1);
      mv[4 * k + 0] = (unsigned)sv.x | ((unsigned)(dv.x & 255) << 17) | (p0 << 25);
      mv[4 * k + 1] = (unsigned)sv.y | ((unsigned)(dv.y & 255) << 17) | (p1 << 25);
      mv[4 * k + 2] = (unsigned)sv.z | ((unsigned)(dv.z & 255) << 17) | (p2 << 25);
      mv[4 * k + 3] = (unsigned)sv.w | ((unsigned)(dv.w & 255) << 17) | (p3 << 25);
      mb[4 * k + 0] = (unsigned short)b0;
      mb[4 * k + 1] = (unsigned short)b1_;
      mb[4 * k + 2] = (unsigned short)b2;
      mb[4 * k + 3] = (unsigned short)b3;
    } else {
      mb[4 * k + 0] = 0xFFFF; mb[4 * k + 1] = 0xFFFF;
      mb[4 * k + 2] = 0xFFFF; mb[4 * k + 3] = 0xFFFF;
    }
  }
  __syncthreads();
  for (int b = tid; b < NBUCKET; b += 256) {
    int h = hist[b];
    gbase[b] = h ? atomicAdd(&gcur[b * GCS], h) : 0;  // one claim per (block,bucket)
  }
  __syncthreads();
#pragma unroll
  for (int k = 0; k < 32; ++k) {
    if (mb[k] != 0xFFFF) {
      int b = mb[k];
      unsigned v = mv[k];
      unsigned pos = (unsigned)gbase[b] + (v >> 25);
      if (pos < BCAP) eb[(size_t)b * BCAP + pos] = v & 0x01FFFFFFu;
    }
  }
}

// ---------------- pass 2: per-bucket counting sort + self-edge + pad-to-8 --------
// Node n's run: [rs[n], re[n]) real (self first), pads == N_NODES to a multiple
// of 8, 16-entry guard after the bucket total. Also emits dis, xd = x4*dis.
// NOW 512 threads/block (8 waves): hist/scatter/writeback loops halve their
// trip counts; the 256-wide scan runs on waves 0-3 (wave-uniform predication,
// no divergent barriers). 391 blocks @ 48KB LDS were latency-starved at 4 waves.

__global__ void __launch_bounds__(512) k_part2(unsigned int* __restrict__ eb,
                                               const int* __restrict__ gcur,
                                               int* __restrict__ rs, int* __restrict__ re,
                                               float* __restrict__ dis,
                                               const float4* __restrict__ x4,
                                               float4* __restrict__ xd) {
  __shared__ int hist[256], scn[256], cur[256];
  __shared__ int wsum[4];
  __shared__ int tot;
  __shared__ unsigned int stage[BCAP];
  int b = blockIdx.x, tid = threadIdx.x;
  int lane = tid & 63, wid = tid >> 6;   // wid 0..7
  int n0 = b << 8;
  int cnt = gcur[b * GCS];
  int base = b * BCAP;
  if (tid < 256) { hist[tid] = 0; cur[tid] = 0; }
  __syncthreads();
  for (int i = tid; i < cnt; i += 512)
    atomicAdd(&hist[eb[base + i] >> 17], 1);
  __syncthreads();
  int n = n0 + tid;
  int deg = (tid < 256) ? hist[tid] : 0;
  int slots = (tid < 256 && n < N_NODES) ? ((deg + 1 + 7) & ~7) : 0;
  // inclusive scan of slots over the 256 node-threads: shfl within waves 0-3
  int v = slots;
  if (wid < 4) {
#pragma unroll
    for (int off = 1; off < 64; off <<= 1) {
      int t = __shfl_up(v, off);
      if (lane >= off) v += t;
    }
    if (lane == 63) wsum[wid] = v;
  }
  __syncthreads();
  int x = v;
  if (wid < 4) {
#pragma unroll
    for (int w2 = 0; w2 < 3; ++w2)
      if (wid > w2) x += wsum[w2];
  }
  int excl = x - slots;
  if (tid == 255) tot = x;
  if (tid < 256 && n < N_NODES) {
    rs[n]  = base + excl;
    re[n]  = base + excl + deg + 1;
    float dn = rsqrtf((float)(deg + 1));
    dis[n] = dn;
    float4 xv = x4[n];
    float4 w; w.x = xv.x * dn; w.y = xv.y * dn; w.z = xv.z * dn; w.w = xv.w * dn;
    xd[n] = w;
    stage[excl] = (unsigned)n;                    // self edge
    for (int i = deg + 1; i < slots; ++i)
      stage[excl + i] = (unsigned)N_NODES;        // zero-row pads
  }
  if (b == 0 && tid == 0) xd[N_NODES] = make_float4(0.f, 0.f, 0.f, 0.f);
  if (tid < 256) scn[tid] = excl + 1;             // in-edge start
  __syncthreads();
  for (int i = tid; i < cnt; i += 512) {
    unsigned v2 = eb[base + i];
    unsigned low = v2 >> 17;
    int lpos = scn[low] + atomicAdd(&cur[low], 1);
    stage[lpos] = v2 & 0x1FFFFu;
  }
  __syncthreads();
  int total = tot;
  for (int i = tid; i < total; i += 512)
    eb[base + i] = stage[i];     // eb is now padded CSR (src ids by dst node)
  if (tid < 16) {                // guard pads for k_agg's prefetch over-read
    int gp = total + tid;
    if (gp < BCAP) eb[base + gp] = (unsigned)N_NODES;
  }
}

// ---------------- Layer 1 fused: aggregate xd + transform + bf16 store ----------
// 4 threads per node (p = gt&3). Thread p reads csr dwords e0+4t+p (slots are
// multiples of 8; pads hit xd's zero row), shfl_xor combine, then writes
// feature slice [16p, 16p+16) of h1s[n] = bf16(relu(b1 + agg·W1) * dis[n]).

__global__ void __launch_bounds__(256) k_l1(const float4* __restrict__ xd,
                                            const float* __restrict__ dis,
                                            const int* __restrict__ rs,
                                            const int* __restrict__ re,
                                            const int* __restrict__ csr,
                                            const float* __restrict__ W1,
                                            const float* __restrict__ b1,
                                            unsigned int* __restrict__ h1o) {
  int gt = blockIdx.x * 256 + threadIdx.x;
  int nid = gt >> 2, p = gt & 3;
  if (nid > N_NODES) return;
  if (nid == N_NODES) {                       // zero row (pad target for k_agg)
    uint4 z = make_uint4(0u, 0u, 0u, 0u);
    uint4* op = (uint4*)(h1o + nid * 32 + p * 8);
    op[0] = z; op[1] = z;
    return;
  }
  int e0 = rs[nid];
  int it4 = ((re[nid] - e0 + 7) & ~7) >> 2;   // dword quads per thread-pass
  const int* cp = csr + e0 + p;
  float ax = 0.f, ay = 0.f, az = 0.f, aw = 0.f;
#pragma unroll 4
  for (int t = 0; t < it4; ++t) {
    int s = cp[t << 2];
    float4 v = xd[s];
    ax += v.x; ay += v.y; az += v.z; aw += v.w;
  }
  ax += __shfl_xor(ax, 1); ax += __shfl_xor(ax, 2);
  ay += __shfl_xor(ay, 1); ay += __shfl_xor(ay, 2);
  az += __shfl_xor(az, 1); az += __shfl_xor(az, 2);
  aw += __shfl_xor(aw, 1); aw += __shfl_xor(aw, 2);
  float dn = dis[nid];
  ax *= dn; ay *= dn; az *= dn; aw *= dn;     // agg1[nid]
  int j0 = p << 4;
  unsigned ou[8];
#pragma unroll
  for (int j2 = 0; j2 < 8; ++j2) {
    int j = j0 + j2 * 2;
    float s0 = b1[j]     + ax * W1[j]     + ay * W1[64 + j]     + az * W1[128 + j]     + aw * W1[192 + j];
    float s1 = b1[j + 1] + ax * W1[j + 1] + ay * W1[64 + j + 1] + az * W1[128 + j + 1] + aw * W1[192 + j + 1];
    unsigned u0 = f2bf(fmaxf(s0, 0.f) * dn);
    unsigned u1 = f2bf(fmaxf(s1, 0.f) * dn);
    ou[j2] = u0 | (u1 << 16);
  }
  uint4* op = (uint4*)(h1o + nid * 32 + p * 8);
  op[0] = make_uint4(ou[0], ou[1], ou[2], ou[3]);
  op[1] = make_uint4(ou[4], ou[5], ou[6], ou[7]);
}

// ---------------- Layer-2 aggregation: 2-deep pipelined gather (r1 proven) ----
// Wave per node. Lane l: g = l>>3 (edge subgroup 0..7), c = l&7 (uint4 chunk).
// Stores agg row as bf16 (identical precision: k_final rounds to bf16 anyway).

__device__ inline void acc_bf2(float& a0, float& a1, unsigned u) {
  a0 += __uint_as_float(u << 16);
  a1 += __uint_as_float(u & 0xffff0000u);
}

__global__ void __launch_bounds__(256)
k_agg(const __hip_bfloat16* __restrict__ h1s, const float* __restrict__ dis,
      const int* __restrict__ rs, const int* __restrict__ re,
      const int* __restrict__ csr, unsigned short* __restrict__ aggb) {
  int l = threadIdx.x & 63;
  int w = threadIdx.x >> 6;
  int n = blockIdx.x * 4 + w;   // grid = N/4 exactly
  int g = l >> 3;
  int c = l & 7;

  const unsigned int* h32 = (const unsigned int*)h1s;
  int e0 = rs[n];
  int iter = (re[n] - e0 + 7) >> 3;           // padded 8-blocks, >= 1
  const int* cb = csr + e0 + g;
  int coff = c << 2;                          // dword offset of feature chunk

  float a0 = 0.f, a1 = 0.f, a2 = 0.f, a3 = 0.f;
  float a4 = 0.f, a5 = 0.f, a6 = 0.f, a7 = 0.f;
  int sc = cb[0];                             // iter 0 edge id
  int sn = cb[8];                             // iter 1 (guard-safe)
  uint4 u = *(const uint4*)(h32 + (sc << 5) + coff);
  for (int it = 1; it < iter; ++it) {
    int sf = cb[(it + 1) << 3];               // 2-ahead csr (guard-safe)
    uint4 r = *(const uint4*)(h32 + (sn << 5) + coff);
    acc_bf2(a0, a1, u.x); acc_bf2(a2, a3, u.y);
    acc_bf2(a4, a5, u.z); acc_bf2(a6, a7, u.w);
    u = r; sn = sf;
  }
  acc_bf2(a0, a1, u.x); acc_bf2(a2, a3, u.y);
  acc_bf2(a4, a5, u.z); acc_bf2(a6, a7, u.w);

  // reduce across the 8 edge-subgroups (lane bits 3,4,5)
#define RED3(a) a += __shfl_xor(a, 8); a += __shfl_xor(a, 16); a += __shfl_xor(a, 32);
  RED3(a0) RED3(a1) RED3(a2) RED3(a3) RED3(a4) RED3(a5) RED3(a6) RED3(a7)
#undef RED3

  float dn = dis[n];
  if (l < 8) {                                // lane l == chunk c: feats 8l..8l+7
    unsigned q0 = f2bf(a0 * dn) | (f2bf(a1 * dn) << 16);
    unsigned q1 = f2bf(a2 * dn) | (f2bf(a3 * dn) << 16);
    unsigned q2 = f2bf(a4 * dn) | (f2bf(a5 * dn) << 16);
    unsigned q3 = f2bf(a6 * dn) | (f2bf(a7 * dn) << 16);
    uint4* ap = (uint4*)(aggb + (size_t)n * 64 + (l << 3));
    *ap = make_uint4(q0, q1, q2, q3);
  }
}

// ---------------- final: MFMA GEMV  t = relu(aggb.W2 + b2); out = t.Wf + bf ----
// Wave = 16 nodes. mfma_f32_16x16x32_bf16: A lane = aggb[n0+(l&15)][(l>>4)*8+j]
// (direct ushort8 load, already bf16), B lane = bf16(W2[k][nt*16+(l&15)]),
// C layout (m89-verified): col = lane&15, row = (lane>>4)*4 + r.

__global__ void __launch_bounds__(256)
k_final(const unsigned short* __restrict__ aggb, const float* __restrict__ W2,
        const float* __restrict__ b2, const float* __restrict__ Wf,
        const float* __restrict__ bf, float* __restrict__ out) {
  int lane = threadIdx.x & 63;
  int wv = (blockIdx.x << 2) + (threadIdx.x >> 6);   // tile 0..KF_TILES-1
  if (wv >= KF_TILES) return;
  int n0 = wv << 4;
  int m = lane & 15;
  int kg = lane >> 4;                                // 0..3

  // B fragments: W2[k][n], k = kt*32 + kg*8 + j, n = nt*16 + m
  short8 bfr[2][4];
#pragma unroll
  for (int kt = 0; kt < 2; ++kt) {
#pragma unroll
    for (int nt = 0; nt < 4; ++nt) {
      short8 t;
#pragma unroll
      for (int j = 0; j < 8; ++j) {
        int k = kt * 32 + kg * 8 + j;
        t[j] = (short)f2bf(W2[k * 64 + nt * 16 + m]);
      }
      bfr[kt][nt] = t;
    }
  }
  // A fragments: row n0+m, k = kt*32 + kg*8 + j  (16-B aligned ushort8 loads)
  const unsigned short* ar = aggb + (size_t)(n0 + m) * 64 + kg * 8;
  short8 a0 = *(const short8*)(ar);
  short8 a1 = *(const short8*)(ar + 32);

  f32x4 z = {0.f, 0.f, 0.f, 0.f};
  f32x4 acc0 = z, acc1 = z, acc2 = z, acc3 = z;
  acc0 = __builtin_amdgcn_mfma_f32_16x16x32_bf16(a0, bfr[0][0], acc0, 0, 0, 0);
  acc1 = __builtin_amdgcn_mfma_f32_16x16x32_bf16(a0, bfr[0][1], acc1, 0, 0, 0);
  acc2 = __builtin_amdgcn_mfma_f32_16x16x32_bf16(a0, bfr[0][2], acc2, 0, 0, 0);
  acc3 = __builtin_amdgcn_mfma_f32_16x16x32_bf16(a0, bfr[0][3], acc3, 0, 0, 0);
  acc0 = __builtin_amdgcn_mfma_f32_16x16x32_bf16(a1, bfr[1][0], acc0, 0, 0, 0);
  acc1 = __builtin_amdgcn_mfma_f32_16x16x32_bf16(a1, bfr[1][1], acc1, 0, 0, 0);
  acc2 = __builtin_amdgcn_mfma_f32_16x16x32_bf16(a1, bfr[1][2], acc2, 0, 0, 0);
  acc3 = __builtin_amdgcn_mfma_f32_16x16x32_bf16(a1, bfr[1][3], acc3, 0, 0, 0);

  // epilogue: for each nt, col = nt*16+m; rows kg*4+r
  float p0[4] = {0.f, 0.f, 0.f, 0.f};
  float p1[4] = {0.f, 0.f, 0.f, 0.f};
#pragma unroll
  for (int nt = 0; nt < 4; ++nt) {
    int col = nt * 16 + m;
    float bb = b2[col];
    float w0 = Wf[col * 2 + 0];
    float w1 = Wf[col * 2 + 1];
    f32x4 av = (nt == 0) ? acc0 : (nt == 1) ? acc1 : (nt == 2) ? acc2 : acc3;
#pragma unroll
    for (int r = 0; r < 4; ++r) {
      float tv = fmaxf(av[r] + bb, 0.f);
      p0[r] = fmaf(tv, w0, p0[r]);
      p1[r] = fmaf(tv, w1, p1[r]);
    }
  }
  // reduce across the 16 columns (lane bits 0..3)
#pragma unroll
  for (int r = 0; r < 4; ++r) {
    p0[r] += __shfl_xor(p0[r], 1); p0[r] += __shfl_xor(p0[r], 2);
    p0[r] += __shfl_xor(p0[r], 4); p0[r] += __shfl_xor(p0[r], 8);
    p1[r] += __shfl_xor(p1[r], 1); p1[r] += __shfl_xor(p1[r], 2);
    p1[r] += __shfl_xor(p1[r], 4); p1[r] += __shfl_xor(p1[r], 8);
  }
  float bf0 = bf[0], bf1 = bf[1];
  int rowb = n0 + kg * 4;
  if (m == 0) *(float2*)(out + (rowb + 0) * 2) = make_float2(p0[0] + bf0, p1[0] + bf1);
  if (m == 1) *(float2*)(out + (rowb + 1) * 2) = make_float2(p0[1] + bf0, p1[1] + bf1);
  if (m == 2) *(float2*)(out + (rowb + 2) * 2) = make_float2(p0[2] + bf0, p1[2] + bf1);
  if (m == 3) *(float2*)(out + (rowb + 3) * 2) = make_float2(p0[3] + bf0, p1[3] + bf1);
}

// ---------------- launch ----------------

extern "C" void kernel_launch(void* const* d_in, const int* in_sizes, int n_in,
                              void* d_out, int out_size, void* d_ws, size_t ws_size,
                              hipStream_t stream) {
  const float* x  = (const float*)d_in[0];
  const int*   ei = (const int*)d_in[1];     // [2, E] row-major, int32
  const float* W1 = (const float*)d_in[2];
  const float* b1 = (const float*)d_in[3];
  const float* W2 = (const float*)d_in[4];
  const float* b2 = (const float*)d_in[5];
  const float* Wf = (const float*)d_in[6];
  const float* bf = (const float*)d_in[7];
  float* out = (float*)d_out;

  const int* srcv = ei;
  const int* dstv = ei + N_EDGES;

  char* p = (char*)d_ws;
  auto take = [&](size_t bytes) { char* r = p; p += (bytes + 255) & ~(size_t)255; return r; };
  int*          gcur = (int*)take((size_t)NBUCKET * GCS * 4);                   // 64-B strided counters
  unsigned int* eb   = (unsigned int*)take((size_t)NBUCKET * BCAP * 4 + 512);  // padded CSR
  int*          rs   = (int*)take((size_t)N_NODES * 4);
  int*          re   = (int*)take((size_t)N_NODES * 4);
  float*        dis  = (float*)take((size_t)N_NODES * 4);
  float4*       xd   = (float4*)take((size_t)(N_NODES + 1) * 16);               // + zero row
  __hip_bfloat16* h1s = (__hip_bfloat16*)take((size_t)(N_NODES + 1) * 64 * 2);  // + zero row
  unsigned short* aggb = (unsigned short*)take((size_t)N_NODES * 64 * 2);       // bf16, 12.8 MB

  (void)hipMemsetAsync(gcur, 0, (size_t)NBUCKET * GCS * 4, stream);
  k_pass1<<<NPB, 256, 0, stream>>>(srcv, dstv, gcur, eb);
  k_part2<<<NBUCKET, 512, 0, stream>>>(eb, gcur, rs, re, dis, (const float4*)x, xd);
  const int* csr = (const int*)eb;
  k_l1<<<((N_NODES + 1) * 4 + 255) / 256, 256, 0, stream>>>(xd, dis, rs, re, csr, W1, b1, (unsigned int*)h1s);
  k_agg<<<N_NODES / 4, 256, 0, stream>>>(h1s, dis, rs, re, csr, aggb);
  k_final<<<KF_BLOCKS, 256, 0, stream>>>(aggb, W2, b2, Wf, bf, out);
}

// Round 10
// 212.706 us; speedup vs baseline: 1.1658x; 1.0166x over previous
//
#include <hip/hip_runtime.h>
#include <hip/hip_bf16.h>

#define N_NODES 100000
#define N_EDGES 3200000
#define NB ((N_NODES + 255) / 256)   // 391
#define NBUCKET NB                   // coarse bucket = dst>>8
#define EPB 8192                     // edges per k_pass1 block
#define NPB ((N_EDGES + EPB - 1) / EPB)  // 391 blocks
#define BCAP 11264                   // per-bucket cap incl self+pad(8)+guard; mean ~9344, 20 sigma
#define KF_TILES (N_NODES / 16)      // 6250 MFMA tiles (16 nodes each), exact
#define KF_BLOCKS ((KF_TILES + 3) / 4)  // 1563 blocks of 4 waves
#define GCS 16                       // gcur stride (ints): 1 counter per 64-B line
#define NSH 8                        // src shards (src>>14): h1s slice ~2.1 MB, L2-resident

typedef short short8 __attribute__((ext_vector_type(8)));
typedef float f32x4 __attribute__((ext_vector_type(4)));

// RNE float->bf16 bits (matches __float2bfloat16 for finite values)
__device__ inline unsigned f2bf(float f) {
  unsigned x = __float_as_uint(f);
  return (x + 0x7FFFu + ((x >> 16) & 1u)) >> 16;
}

// ---------------- pass 1: register-resident coarse partition ----------------
// item: bits[16:0] = src, bits[24:17] = dst & 255 (bucket = dst>>8).
// Single LDS-atomic round: per-item position packed into bits[31:25].

__global__ void __launch_bounds__(256) k_pass1(const int* __restrict__ src,
                                               const int* __restrict__ dst,
                                               int* __restrict__ gcur,
                                               unsigned int* __restrict__ eb) {
  __shared__ int hist[NBUCKET];
  __shared__ int gbase[NBUCKET];
  int tid = threadIdx.x;
  int base = blockIdx.x * EPB;
  int cnt = min(EPB, N_EDGES - base);   // multiple of 4
  int n4 = cnt >> 2;
  for (int i = tid; i < NBUCKET; i += 256) hist[i] = 0;
  __syncthreads();
  const int4* d4 = (const int4*)(dst + base);
  const int4* s4 = (const int4*)(src + base);
  unsigned mv[32];
  unsigned short mb[32];
#pragma unroll
  for (int k = 0; k < 8; ++k) {
    int i = tid + (k << 8);
    if (i < n4) {
      int4 dv = d4[i];
      int4 sv = s4[i];
      int b0 = dv.x >> 8, b1_ = dv.y >> 8, b2 = dv.z >> 8, b3 = dv.w >> 8;
      unsigned p0 = atomicAdd(&hist[b0], 1);
      unsigned p1 = atomicAdd(&hist[b1_], 1);
      unsigned p2 = atomicAdd(&hist[b2], 1);
      unsigned p3 = atomicAdd(&hist[b3], 1);
      mv[4 * k + 0] = (unsigned)sv.x | ((unsigned)(dv.x & 255) << 17) | (p0 << 25);
      mv[4 * k + 1] = (unsigned)sv.y | ((unsigned)(dv.y & 255) << 17) | (p1 << 25);
      mv[4 * k + 2] = (unsigned)sv.z | ((unsigned)(dv.z & 255) << 17) | (p2 << 25);
      mv[4 * k + 3] = (unsigned)sv.w | ((unsigned)(dv.w & 255) << 17) | (p3 << 25);
      mb[4 * k + 0] = (unsigned short)b0;
      mb[4 * k + 1] = (unsigned short)b1_;
      mb[4 * k + 2] = (unsigned short)b2;
      mb[4 * k + 3] = (unsigned short)b3;
    } else {
      mb[4 * k + 0] = 0xFFFF; mb[4 * k + 1] = 0xFFFF;
      mb[4 * k + 2] = 0xFFFF; mb[4 * k + 3] = 0xFFFF;
    }
  }
  __syncthreads();
  for (int b = tid; b < NBUCKET; b += 256) {
    int h = hist[b];
    gbase[b] = h ? atomicAdd(&gcur[b * GCS], h) : 0;  // one claim per (block,bucket)
  }
  __syncthreads();
#pragma unroll
  for (int k = 0; k < 32; ++k) {
    if (mb[k] != 0xFFFF) {
      int b = mb[k];
      unsigned v = mv[k];
      unsigned pos = (unsigned)gbase[b] + (v >> 25);
      if (pos < BCAP) eb[(size_t)b * BCAP + pos] = v & 0x01FFFFFFu;
    }
  }
}

// ---------------- pass 2: per-bucket counting sort, SHARD-ORDERED runs ---------
// Sort key widened to (node, src>>14): node n's run is [rs, re) with self edge
// first, then in-edges grouped by src shard (8 shards x ~2.1 MB of h1s). k_agg
// waves then sweep shards 0..7 in order -> the instantaneous gather working set
// concentrates on a few L2-resident shards (soft phase coherence) instead of
// the full 12.8 MB h1s table. Pads to multiple of 8 + 16-entry guard unchanged.
// 512 threads (R9-proven). LDS: 2x8KB (hist2/sbase) + 45KB stage.

__global__ void __launch_bounds__(512) k_part2(unsigned int* __restrict__ eb,
                                               const int* __restrict__ gcur,
                                               int* __restrict__ rs, int* __restrict__ re,
                                               float* __restrict__ dis,
                                               const float4* __restrict__ x4,
                                               float4* __restrict__ xd) {
  __shared__ int hist2[256 * NSH];   // counts per (node, shard)
  __shared__ int sbase[256 * NSH];   // scatter cursors per (node, shard)
  __shared__ int wsum[4];
  __shared__ int tot;
  __shared__ unsigned int stage[BCAP];
  int b = blockIdx.x, tid = threadIdx.x;
  int lane = tid & 63, wid = tid >> 6;   // wid 0..7
  int n0 = b << 8;
  int cnt = gcur[b * GCS];
  int base = b * BCAP;
  for (int i = tid; i < 256 * NSH; i += 512) hist2[i] = 0;
  __syncthreads();
  for (int i = tid; i < cnt; i += 512) {
    unsigned v2 = eb[base + i];
    atomicAdd(&hist2[((v2 >> 17) << 3) + ((v2 & 0x1FFFFu) >> 14)], 1);
  }
  __syncthreads();
  int n = n0 + tid;
  int deg = 0;
  int hs[NSH];
  if (tid < 256) {
#pragma unroll
    for (int s = 0; s < NSH; ++s) { hs[s] = hist2[(tid << 3) + s]; deg += hs[s]; }
  }
  int slots = (tid < 256 && n < N_NODES) ? ((deg + 1 + 7) & ~7) : 0;
  // inclusive scan of slots over the 256 node-threads: shfl within waves 0-3
  int v = slots;
  if (wid < 4) {
#pragma unroll
    for (int off = 1; off < 64; off <<= 1) {
      int t = __shfl_up(v, off);
      if (lane >= off) v += t;
    }
    if (lane == 63) wsum[wid] = v;
  }
  __syncthreads();
  int x = v;
  if (wid < 4) {
#pragma unroll
    for (int w2 = 0; w2 < 3; ++w2)
      if (wid > w2) x += wsum[w2];
  }
  int excl = x - slots;
  if (tid == 255) tot = x;
  if (tid < 256 && n < N_NODES) {
    rs[n]  = base + excl;
    re[n]  = base + excl + deg + 1;
    float dn = rsqrtf((float)(deg + 1));
    dis[n] = dn;
    float4 xv = x4[n];
    float4 w; w.x = xv.x * dn; w.y = xv.y * dn; w.z = xv.z * dn; w.w = xv.w * dn;
    xd[n] = w;
    stage[excl] = (unsigned)n;                    // self edge first
    for (int i = deg + 1; i < slots; ++i)
      stage[excl + i] = (unsigned)N_NODES;        // zero-row pads
    int o = excl + 1;                             // in-edges: shard-grouped
#pragma unroll
    for (int s = 0; s < NSH; ++s) { sbase[(tid << 3) + s] = o; o += hs[s]; }
  }
  if (b == 0 && tid == 0) xd[N_NODES] = make_float4(0.f, 0.f, 0.f, 0.f);
  __syncthreads();
  for (int i = tid; i < cnt; i += 512) {
    unsigned v2 = eb[base + i];
    unsigned srcv = v2 & 0x1FFFFu;
    int key = ((v2 >> 17) << 3) + (srcv >> 14);
    int lpos = atomicAdd(&sbase[key], 1);
    stage[lpos] = srcv;
  }
  __syncthreads();
  int total = tot;
  for (int i = tid; i < total; i += 512)
    eb[base + i] = stage[i];     // eb is now padded, shard-ordered CSR
  if (tid < 16) {                // guard pads for k_agg's prefetch over-read
    int gp = total + tid;
    if (gp < BCAP) eb[base + gp] = (unsigned)N_NODES;
  }
}

// ---------------- Layer 1 fused: aggregate xd + transform + bf16 store ----------
// 4 threads per node (p = gt&3). Thread p reads csr dwords e0+4t+p (slots are
// multiples of 8; pads hit xd's zero row), shfl_xor combine, then writes
// feature slice [16p, 16p+16) of h1s[n] = bf16(relu(b1 + agg·W1) * dis[n]).

__global__ void __launch_bounds__(256) k_l1(const float4* __restrict__ xd,
                                            const float* __restrict__ dis,
                                            const int* __restrict__ rs,
                                            const int* __restrict__ re,
                                            const int* __restrict__ csr,
                                            const float* __restrict__ W1,
                                            const float* __restrict__ b1,
                                            unsigned int* __restrict__ h1o) {
  int gt = blockIdx.x * 256 + threadIdx.x;
  int nid = gt >> 2, p = gt & 3;
  if (nid > N_NODES) return;
  if (nid == N_NODES) {                       // zero row (pad target for k_agg)
    uint4 z = make_uint4(0u, 0u, 0u, 0u);
    uint4* op = (uint4*)(h1o + nid * 32 + p * 8);
    op[0] = z; op[1] = z;
    return;
  }
  int e0 = rs[nid];
  int it4 = ((re[nid] - e0 + 7) & ~7) >> 2;   // dword quads per thread-pass
  const int* cp = csr + e0 + p;
  float ax = 0.f, ay = 0.f, az = 0.f, aw = 0.f;
#pragma unroll 4
  for (int t = 0; t < it4; ++t) {
    int s = cp[t << 2];
    float4 v = xd[s];
    ax += v.x; ay += v.y; az += v.z; aw += v.w;
  }
  ax += __shfl_xor(ax, 1); ax += __shfl_xor(ax, 2);
  ay += __shfl_xor(ay, 1); ay += __shfl_xor(ay, 2);
  az += __shfl_xor(az, 1); az += __shfl_xor(az, 2);
  aw += __shfl_xor(aw, 1); aw += __shfl_xor(aw, 2);
  float dn = dis[nid];
  ax *= dn; ay *= dn; az *= dn; aw *= dn;     // agg1[nid]
  int j0 = p << 4;
  unsigned ou[8];
#pragma unroll
  for (int j2 = 0; j2 < 8; ++j2) {
    int j = j0 + j2 * 2;
    float s0 = b1[j]     + ax * W1[j]     + ay * W1[64 + j]     + az * W1[128 + j]     + aw * W1[192 + j];
    float s1 = b1[j + 1] + ax * W1[j + 1] + ay * W1[64 + j + 1] + az * W1[128 + j + 1] + aw * W1[192 + j + 1];
    unsigned u0 = f2bf(fmaxf(s0, 0.f) * dn);
    unsigned u1 = f2bf(fmaxf(s1, 0.f) * dn);
    ou[j2] = u0 | (u1 << 16);
  }
  uint4* op = (uint4*)(h1o + nid * 32 + p * 8);
  op[0] = make_uint4(ou[0], ou[1], ou[2], ou[3]);
  op[1] = make_uint4(ou[4], ou[5], ou[6], ou[7]);
}

// ---------------- Layer-2 aggregation: 2-deep pipelined gather (r1 proven) ----
// Wave per node. Lane l: g = l>>3 (edge subgroup 0..7), c = l&7 (uint4 chunk).
// Runs are shard-ordered (part2) so all waves sweep h1s shards 0..7 in order.
// Stores agg row as bf16 (identical precision: k_final rounds to bf16 anyway).

__device__ inline void acc_bf2(float& a0, float& a1, unsigned u) {
  a0 += __uint_as_float(u << 16);
  a1 += __uint_as_float(u & 0xffff0000u);
}

__global__ void __launch_bounds__(256)
k_agg(const __hip_bfloat16* __restrict__ h1s, const float* __restrict__ dis,
      const int* __restrict__ rs, const int* __restrict__ re,
      const int* __restrict__ csr, unsigned short* __restrict__ aggb) {
  int l = threadIdx.x & 63;
  int w = threadIdx.x >> 6;
  int n = blockIdx.x * 4 + w;   // grid = N/4 exactly
  int g = l >> 3;
  int c = l & 7;

  const unsigned int* h32 = (const unsigned int*)h1s;
  int e0 = rs[n];
  int iter = (re[n] - e0 + 7) >> 3;           // padded 8-blocks, >= 1
  const int* cb = csr + e0 + g;
  int coff = c << 2;                          // dword offset of feature chunk

  float a0 = 0.f, a1 = 0.f, a2 = 0.f, a3 = 0.f;
  float a4 = 0.f, a5 = 0.f, a6 = 0.f, a7 = 0.f;
  int sc = cb[0];                             // iter 0 edge id
  int sn = cb[8];                             // iter 1 (guard-safe)
  uint4 u = *(const uint4*)(h32 + (sc << 5) + coff);
  for (int it = 1; it < iter; ++it) {
    int sf = cb[(it + 1) << 3];               // 2-ahead csr (guard-safe)
    uint4 r = *(const uint4*)(h32 + (sn << 5) + coff);
    acc_bf2(a0, a1, u.x); acc_bf2(a2, a3, u.y);
    acc_bf2(a4, a5, u.z); acc_bf2(a6, a7, u.w);
    u = r; sn = sf;
  }
  acc_bf2(a0, a1, u.x); acc_bf2(a2, a3, u.y);
  acc_bf2(a4, a5, u.z); acc_bf2(a6, a7, u.w);

  // reduce across the 8 edge-subgroups (lane bits 3,4,5)
#define RED3(a) a += __shfl_xor(a, 8); a += __shfl_xor(a, 16); a += __shfl_xor(a, 32);
  RED3(a0) RED3(a1) RED3(a2) RED3(a3) RED3(a4) RED3(a5) RED3(a6) RED3(a7)
#undef RED3

  float dn = dis[n];
  if (l < 8) {                                // lane l == chunk c: feats 8l..8l+7
    unsigned q0 = f2bf(a0 * dn) | (f2bf(a1 * dn) << 16);
    unsigned q1 = f2bf(a2 * dn) | (f2bf(a3 * dn) << 16);
    unsigned q2 = f2bf(a4 * dn) | (f2bf(a5 * dn) << 16);
    unsigned q3 = f2bf(a6 * dn) | (f2bf(a7 * dn) << 16);
    uint4* ap = (uint4*)(aggb + (size_t)n * 64 + (l << 3));
    *ap = make_uint4(q0, q1, q2, q3);
  }
}

// ---------------- final: MFMA GEMV  t = relu(aggb.W2 + b2); out = t.Wf + bf ----
// Wave = 16 nodes. mfma_f32_16x16x32_bf16: A lane = aggb[n0+(l&15)][(l>>4)*8+j]
// (direct ushort8 load, already bf16), B lane = bf16(W2[k][nt*16+(l&15)]),
// C layout (m89-verified): col = lane&15, row = (lane>>4)*4 + r.

__global__ void __launch_bounds__(256)
k_final(const unsigned short* __restrict__ aggb, const float* __restrict__ W2,
        const float* __restrict__ b2, const float* __restrict__ Wf,
        const float* __restrict__ bf, float* __restrict__ out) {
  int lane = threadIdx.x & 63;
  int wv = (blockIdx.x << 2) + (threadIdx.x >> 6);   // tile 0..KF_TILES-1
  if (wv >= KF_TILES) return;
  int n0 = wv << 4;
  int m = lane & 15;
  int kg = lane >> 4;                                // 0..3

  // B fragments: W2[k][n], k = kt*32 + kg*8 + j, n = nt*16 + m
  short8 bfr[2][4];
#pragma unroll
  for (int kt = 0; kt < 2; ++kt) {
#pragma unroll
    for (int nt = 0; nt < 4; ++nt) {
      short8 t;
#pragma unroll
      for (int j = 0; j < 8; ++j) {
        int k = kt * 32 + kg * 8 + j;
        t[j] = (short)f2bf(W2[k * 64 + nt * 16 + m]);
      }
      bfr[kt][nt] = t;
    }
  }
  // A fragments: row n0+m, k = kt*32 + kg*8 + j  (16-B aligned ushort8 loads)
  const unsigned short* ar = aggb + (size_t)(n0 + m) * 64 + kg * 8;
  short8 a0 = *(const short8*)(ar);
  short8 a1 = *(const short8*)(ar + 32);

  f32x4 z = {0.f, 0.f, 0.f, 0.f};
  f32x4 acc0 = z, acc1 = z, acc2 = z, acc3 = z;
  acc0 = __builtin_amdgcn_mfma_f32_16x16x32_bf16(a0, bfr[0][0], acc0, 0, 0, 0);
  acc1 = __builtin_amdgcn_mfma_f32_16x16x32_bf16(a0, bfr[0][1], acc1, 0, 0, 0);
  acc2 = __builtin_amdgcn_mfma_f32_16x16x32_bf16(a0, bfr[0][2], acc2, 0, 0, 0);
  acc3 = __builtin_amdgcn_mfma_f32_16x16x32_bf16(a0, bfr[0][3], acc3, 0, 0, 0);
  acc0 = __builtin_amdgcn_mfma_f32_16x16x32_bf16(a1, bfr[1][0], acc0, 0, 0, 0);
  acc1 = __builtin_amdgcn_mfma_f32_16x16x32_bf16(a1, bfr[1][1], acc1, 0, 0, 0);
  acc2 = __builtin_amdgcn_mfma_f32_16x16x32_bf16(a1, bfr[1][2], acc2, 0, 0, 0);
  acc3 = __builtin_amdgcn_mfma_f32_16x16x32_bf16(a1, bfr[1][3], acc3, 0, 0, 0);

  // epilogue: for each nt, col = nt*16+m; rows kg*4+r
  float p0[4] = {0.f, 0.f, 0.f, 0.f};
  float p1[4] = {0.f, 0.f, 0.f, 0.f};
#pragma unroll
  for (int nt = 0; nt < 4; ++nt) {
    int col = nt * 16 + m;
    float bb = b2[col];
    float w0 = Wf[col * 2 + 0];
    float w1 = Wf[col * 2 + 1];
    f32x4 av = (nt == 0) ? acc0 : (nt == 1) ? acc1 : (nt == 2) ? acc2 : acc3;
#pragma unroll
    for (int r = 0; r < 4; ++r) {
      float tv = fmaxf(av[r] + bb, 0.f);
      p0[r] = fmaf(tv, w0, p0[r]);
      p1[r] = fmaf(tv, w1, p1[r]);
    }
  }
  // reduce across the 16 columns (lane bits 0..3)
#pragma unroll
  for (int r = 0; r < 4; ++r) {
    p0[r] += __shfl_xor(p0[r], 1); p0[r] += __shfl_xor(p0[r], 2);
    p0[r] += __shfl_xor(p0[r], 4); p0[r] += __shfl_xor(p0[r], 8);
    p1[r] += __shfl_xor(p1[r], 1); p1[r] += __shfl_xor(p1[r], 2);
    p1[r] += __shfl_xor(p1[r], 4); p1[r] += __shfl_xor(p1[r], 8);
  }
  float bf0 = bf[0], bf1 = bf[1];
  int rowb = n0 + kg * 4;
  if (m == 0) *(float2*)(out + (rowb + 0) * 2) = make_float2(p0[0] + bf0, p1[0] + bf1);
  if (m == 1) *(float2*)(out + (rowb + 1) * 2) = make_float2(p0[1] + bf0, p1[1] + bf1);
  if (m == 2) *(float2*)(out + (rowb + 2) * 2) = make_float2(p0[2] + bf0, p1[2] + bf1);
  if (m == 3) *(float2*)(out + (rowb + 3) * 2) = make_float2(p0[3] + bf0, p1[3] + bf1);
}

// ---------------- launch ----------------

extern "C" void kernel_launch(void* const* d_in, const int* in_sizes, int n_in,
                              void* d_out, int out_size, void* d_ws, size_t ws_size,
                              hipStream_t stream) {
  const float* x  = (const float*)d_in[0];
  const int*   ei = (const int*)d_in[1];     // [2, E] row-major, int32
  const float* W1 = (const float*)d_in[2];
  const float* b1 = (const float*)d_in[3];
  const float* W2 = (const float*)d_in[4];
  const float* b2 = (const float*)d_in[5];
  const float* Wf = (const float*)d_in[6];
  const float* bf = (const float*)d_in[7];
  float* out = (float*)d_out;

  const int* srcv = ei;
  const int* dstv = ei + N_EDGES;

  char* p = (char*)d_ws;
  auto take = [&](size_t bytes) { char* r = p; p += (bytes + 255) & ~(size_t)255; return r; };
  int*          gcur = (int*)take((size_t)NBUCKET * GCS * 4);                   // 64-B strided counters
  unsigned int* eb   = (unsigned int*)take((size_t)NBUCKET * BCAP * 4 + 512);  // padded CSR
  int*          rs   = (int*)take((size_t)N_NODES * 4);
  int*          re   = (int*)take((size_t)N_NODES * 4);
  float*        dis  = (float*)take((size_t)N_NODES * 4);
  float4*       xd   = (float4*)take((size_t)(N_NODES + 1) * 16);               // + zero row
  __hip_bfloat16* h1s = (__hip_bfloat16*)take((size_t)(N_NODES + 1) * 64 * 2);  // + zero row
  unsigned short* aggb = (unsigned short*)take((size_t)N_NODES * 64 * 2);       // bf16, 12.8 MB

  (void)hipMemsetAsync(gcur, 0, (size_t)NBUCKET * GCS * 4, stream);
  k_pass1<<<NPB, 256, 0, stream>>>(srcv, dstv, gcur, eb);
  k_part2<<<NBUCKET, 512, 0, stream>>>(eb, gcur, rs, re, dis, (const float4*)x, xd);
  const int* csr = (const int*)eb;
  k_l1<<<((N_NODES + 1) * 4 + 255) / 256, 256, 0, stream>>>(xd, dis, rs, re, csr, W1, b1, (unsigned int*)h1s);
  k_agg<<<N_NODES / 4, 256, 0, stream>>>(h1s, dis, rs, re, csr, aggb);
  k_final<<<KF_BLOCKS, 256, 0, stream>>>(aggb, W2, b2, Wf, bf, out);
}

// Round 11
// 208.146 us; speedup vs baseline: 1.1913x; 1.0219x over previous
//
#include <hip/hip_runtime.h>
#include <hip/hip_bf16.h>

#define N_NODES 100000
#define N_EDGES 3200000
#define NB ((N_NODES + 255) / 256)   // 391
#define NBUCKET NB                   // coarse bucket = dst>>8
#define EPB 8192                     // edges per k_pass1 block
#define NPB ((N_EDGES + EPB - 1) / EPB)  // 391 blocks
#define BCAP 11264                   // per-bucket cap incl self+pad(8)+guard; mean ~9344, 20 sigma
#define KF_TILES (N_NODES / 16)      // 6250 MFMA tiles (16 nodes each), exact
#define KF_BLOCKS ((KF_TILES + 3) / 4)  // 1563 blocks of 4 waves
#define GCS 16                       // gcur stride (ints): 1 counter per 64-B line
#define NSH 8                        // src shards (src>>14) in part2's sort key

typedef short short8 __attribute__((ext_vector_type(8)));
typedef float f32x4 __attribute__((ext_vector_type(4)));

// RNE float->bf16 bits (matches __float2bfloat16 for finite values)
__device__ inline unsigned f2bf(float f) {
  unsigned x = __float_as_uint(f);
  return (x + 0x7FFFu + ((x >> 16) & 1u)) >> 16;
}

// ---------------- pass 1: coarse partition with LDS-staged coalesced flush -----
// item: bits[16:0] = src, bits[24:17] = dst & 255 (bucket = dst>>8); per-item
// per-(block,bucket) position packed into bits[31:25] by the LDS-atomic hist.
// NEW: instead of each lane scattering its item to a random bucket address
// (64 transactions/wave), items are bucket-sorted in LDS (sval/sbkt) via a
// hist prefix scan, then flushed in slot order -> consecutive slots within a
// bucket hit consecutive eb addresses (avg run ~21) => ~5x fewer global write
// transactions. LDS ~54 KB, 2 blocks/CU.

__global__ void __launch_bounds__(256) k_pass1(const int* __restrict__ src,
                                               const int* __restrict__ dst,
                                               int* __restrict__ gcur,
                                               unsigned int* __restrict__ eb) {
  __shared__ int hist[NBUCKET];
  __shared__ int gbase[NBUCKET];
  __shared__ int lofs[NBUCKET];
  __shared__ int wsum[4];
  __shared__ unsigned int sval[EPB];
  __shared__ unsigned short sbkt[EPB];
  int tid = threadIdx.x;
  int lane = tid & 63, wid = tid >> 6;
  int base = blockIdx.x * EPB;
  int cnt = min(EPB, N_EDGES - base);   // multiple of 4
  int n4 = cnt >> 2;
  for (int i = tid; i < NBUCKET; i += 256) hist[i] = 0;
  __syncthreads();
  const int4* d4 = (const int4*)(dst + base);
  const int4* s4 = (const int4*)(src + base);
  unsigned mv[32];
  unsigned short mb[32];
#pragma unroll
  for (int k = 0; k < 8; ++k) {
    int i = tid + (k << 8);
    if (i < n4) {
      int4 dv = d4[i];
      int4 sv = s4[i];
      int b0 = dv.x >> 8, b1_ = dv.y >> 8, b2 = dv.z >> 8, b3 = dv.w >> 8;
      unsigned p0 = atomicAdd(&hist[b0], 1);
      unsigned p1 = atomicAdd(&hist[b1_], 1);
      unsigned p2 = atomicAdd(&hist[b2], 1);
      unsigned p3 = atomicAdd(&hist[b3], 1);
      mv[4 * k + 0] = (unsigned)sv.x | ((unsigned)(dv.x & 255) << 17) | (p0 << 25);
      mv[4 * k + 1] = (unsigned)sv.y | ((unsigned)(dv.y & 255) << 17) | (p1 << 25);
      mv[4 * k + 2] = (unsigned)sv.z | ((unsigned)(dv.z & 255) << 17) | (p2 << 25);
      mv[4 * k + 3] = (unsigned)sv.w | ((unsigned)(dv.w & 255) << 17) | (p3 << 25);
      mb[4 * k + 0] = (unsigned short)b0;
      mb[4 * k + 1] = (unsigned short)b1_;
      mb[4 * k + 2] = (unsigned short)b2;
      mb[4 * k + 3] = (unsigned short)b3;
    } else {
      mb[4 * k + 0] = 0xFFFF; mb[4 * k + 1] = 0xFFFF;
      mb[4 * k + 2] = 0xFFFF; mb[4 * k + 3] = 0xFFFF;
    }
  }
  __syncthreads();
  // claim global ranges (one atomic per (block,bucket))
  for (int b = tid; b < NBUCKET; b += 256) {
    int h = hist[b];
    gbase[b] = h ? atomicAdd(&gcur[b * GCS], h) : 0;
  }
  // prefix scan of hist (bucket-index order) -> lofs; 2 buckets per thread
  int b0i = 2 * tid, b1i = 2 * tid + 1;
  int h0 = (b0i < NBUCKET) ? hist[b0i] : 0;
  int h1 = (b1i < NBUCKET) ? hist[b1i] : 0;
  int v = h0 + h1;
#pragma unroll
  for (int off = 1; off < 64; off <<= 1) {
    int t = __shfl_up(v, off);
    if (lane >= off) v += t;
  }
  if (lane == 63) wsum[wid] = v;
  __syncthreads();
  int x = v;
#pragma unroll
  for (int w2 = 0; w2 < 3; ++w2)
    if (wid > w2) x += wsum[w2];
  int excl = x - (h0 + h1);
  if (b0i < NBUCKET) lofs[b0i] = excl;
  if (b1i < NBUCKET) lofs[b1i] = excl + h0;
  __syncthreads();
  // bucket-sorted LDS scatter: slot = lofs[b] + per-bucket position
#pragma unroll
  for (int k = 0; k < 32; ++k) {
    if (mb[k] != 0xFFFF) {
      int b = mb[k];
      unsigned m = mv[k];
      int slot = lofs[b] + (int)(m >> 25);
      sval[slot] = m & 0x01FFFFFFu;
      sbkt[slot] = (unsigned short)b;
    }
  }
  __syncthreads();
  // coalesced flush: consecutive slots in a bucket -> consecutive eb addresses
  for (int i = tid; i < cnt; i += 256) {
    int b = sbkt[i];
    int pos = gbase[b] + (i - lofs[b]);
    if (pos < BCAP) eb[(size_t)b * BCAP + pos] = sval[i];
  }
}

// ---------------- pass 2: per-bucket counting sort, SHARD-ORDERED runs ---------
// Sort key (node, src>>14): node n's run is [rs, re) with self edge first, then
// in-edges grouped by src shard. Pads to multiple of 8 + 16-entry guard.
// 512 threads (R9-proven).

__global__ void __launch_bounds__(512) k_part2(unsigned int* __restrict__ eb,
                                               const int* __restrict__ gcur,
                                               int* __restrict__ rs, int* __restrict__ re,
                                               float* __restrict__ dis,
                                               const float4* __restrict__ x4,
                                               float4* __restrict__ xd) {
  __shared__ int hist2[256 * NSH];   // counts per (node, shard)
  __shared__ int sbase[256 * NSH];   // scatter cursors per (node, shard)
  __shared__ int wsum[4];
  __shared__ int tot;
  __shared__ unsigned int stage[BCAP];
  int b = blockIdx.x, tid = threadIdx.x;
  int lane = tid & 63, wid = tid >> 6;   // wid 0..7
  int n0 = b << 8;
  int cnt = gcur[b * GCS];
  int base = b * BCAP;
  for (int i = tid; i < 256 * NSH; i += 512) hist2[i] = 0;
  __syncthreads();
  for (int i = tid; i < cnt; i += 512) {
    unsigned v2 = eb[base + i];
    atomicAdd(&hist2[((v2 >> 17) << 3) + ((v2 & 0x1FFFFu) >> 14)], 1);
  }
  __syncthreads();
  int n = n0 + tid;
  int deg = 0;
  int hs[NSH];
  if (tid < 256) {
#pragma unroll
    for (int s = 0; s < NSH; ++s) { hs[s] = hist2[(tid << 3) + s]; deg += hs[s]; }
  }
  int slots = (tid < 256 && n < N_NODES) ? ((deg + 1 + 7) & ~7) : 0;
  // inclusive scan of slots over the 256 node-threads: shfl within waves 0-3
  int v = slots;
  if (wid < 4) {
#pragma unroll
    for (int off = 1; off < 64; off <<= 1) {
      int t = __shfl_up(v, off);
      if (lane >= off) v += t;
    }
    if (lane == 63) wsum[wid] = v;
  }
  __syncthreads();
  int x = v;
  if (wid < 4) {
#pragma unroll
    for (int w2 = 0; w2 < 3; ++w2)
      if (wid > w2) x += wsum[w2];
  }
  int excl = x - slots;
  if (tid == 255) tot = x;
  if (tid < 256 && n < N_NODES) {
    rs[n]  = base + excl;
    re[n]  = base + excl + deg + 1;
    float dn = rsqrtf((float)(deg + 1));
    dis[n] = dn;
    float4 xv = x4[n];
    float4 w; w.x = xv.x * dn; w.y = xv.y * dn; w.z = xv.z * dn; w.w = xv.w * dn;
    xd[n] = w;
    stage[excl] = (unsigned)n;                    // self edge first
    for (int i = deg + 1; i < slots; ++i)
      stage[excl + i] = (unsigned)N_NODES;        // zero-row pads
    int o = excl + 1;                             // in-edges: shard-grouped
#pragma unroll
    for (int s = 0; s < NSH; ++s) { sbase[(tid << 3) + s] = o; o += hs[s]; }
  }
  if (b == 0 && tid == 0) xd[N_NODES] = make_float4(0.f, 0.f, 0.f, 0.f);
  __syncthreads();
  for (int i = tid; i < cnt; i += 512) {
    unsigned v2 = eb[base + i];
    unsigned srcv = v2 & 0x1FFFFu;
    int key = ((v2 >> 17) << 3) + (srcv >> 14);
    int lpos = atomicAdd(&sbase[key], 1);
    stage[lpos] = srcv;
  }
  __syncthreads();
  int total = tot;
  for (int i = tid; i < total; i += 512)
    eb[base + i] = stage[i];     // eb is now padded, shard-ordered CSR
  if (tid < 16) {                // guard pads for k_agg's prefetch over-read
    int gp = total + tid;
    if (gp < BCAP) eb[base + gp] = (unsigned)N_NODES;
  }
}

// ---------------- Layer 1 fused: aggregate xd + transform + bf16 store ----------
// 4 threads per node (p = gt&3). Thread p reads csr dwords e0+4t+p (slots are
// multiples of 8; pads hit xd's zero row), shfl_xor combine, then writes
// feature slice [16p, 16p+16) of h1s[n] = bf16(relu(b1 + agg·W1) * dis[n]).

__global__ void __launch_bounds__(256) k_l1(const float4* __restrict__ xd,
                                            const float* __restrict__ dis,
                                            const int* __restrict__ rs,
                                            const int* __restrict__ re,
                                            const int* __restrict__ csr,
                                            const float* __restrict__ W1,
                                            const float* __restrict__ b1,
                                            unsigned int* __restrict__ h1o) {
  int gt = blockIdx.x * 256 + threadIdx.x;
  int nid = gt >> 2, p = gt & 3;
  if (nid > N_NODES) return;
  if (nid == N_NODES) {                       // zero row (pad target for k_agg)
    uint4 z = make_uint4(0u, 0u, 0u, 0u);
    uint4* op = (uint4*)(h1o + nid * 32 + p * 8);
    op[0] = z; op[1] = z;
    return;
  }
  int e0 = rs[nid];
  int it4 = ((re[nid] - e0 + 7) & ~7) >> 2;   // dword quads per thread-pass
  const int* cp = csr + e0 + p;
  float ax = 0.f, ay = 0.f, az = 0.f, aw = 0.f;
#pragma unroll 4
  for (int t = 0; t < it4; ++t) {
    int s = cp[t << 2];
    float4 v = xd[s];
    ax += v.x; ay += v.y; az += v.z; aw += v.w;
  }
  ax += __shfl_xor(ax, 1); ax += __shfl_xor(ax, 2);
  ay += __shfl_xor(ay, 1); ay += __shfl_xor(ay, 2);
  az += __shfl_xor(az, 1); az += __shfl_xor(az, 2);
  aw += __shfl_xor(aw, 1); aw += __shfl_xor(aw, 2);
  float dn = dis[nid];
  ax *= dn; ay *= dn; az *= dn; aw *= dn;     // agg1[nid]
  int j0 = p << 4;
  unsigned ou[8];
#pragma unroll
  for (int j2 = 0; j2 < 8; ++j2) {
    int j = j0 + j2 * 2;
    float s0 = b1[j]     + ax * W1[j]     + ay * W1[64 + j]     + az * W1[128 + j]     + aw * W1[192 + j];
    float s1 = b1[j + 1] + ax * W1[j + 1] + ay * W1[64 + j + 1] + az * W1[128 + j + 1] + aw * W1[192 + j + 1];
    unsigned u0 = f2bf(fmaxf(s0, 0.f) * dn);
    unsigned u1 = f2bf(fmaxf(s1, 0.f) * dn);
    ou[j2] = u0 | (u1 << 16);
  }
  uint4* op = (uint4*)(h1o + nid * 32 + p * 8);
  op[0] = make_uint4(ou[0], ou[1], ou[2], ou[3]);
  op[1] = make_uint4(ou[4], ou[5], ou[6], ou[7]);
}

// ---------------- Layer-2 aggregation: 2-deep pipelined gather (r1 proven) ----
// Wave per node. Lane l: g = l>>3 (edge subgroup 0..7), c = l&7 (uint4 chunk).
// At the random-128B-line HBM roofline (R10 confirmed: FETCH invariant).

__device__ inline void acc_bf2(float& a0, float& a1, unsigned u) {
  a0 += __uint_as_float(u << 16);
  a1 += __uint_as_float(u & 0xffff0000u);
}

__global__ void __launch_bounds__(256)
k_agg(const __hip_bfloat16* __restrict__ h1s, const float* __restrict__ dis,
      const int* __restrict__ rs, const int* __restrict__ re,
      const int* __restrict__ csr, unsigned short* __restrict__ aggb) {
  int l = threadIdx.x & 63;
  int w = threadIdx.x >> 6;
  int n = blockIdx.x * 4 + w;   // grid = N/4 exactly
  int g = l >> 3;
  int c = l & 7;

  const unsigned int* h32 = (const unsigned int*)h1s;
  int e0 = rs[n];
  int iter = (re[n] - e0 + 7) >> 3;           // padded 8-blocks, >= 1
  const int* cb = csr + e0 + g;
  int coff = c << 2;                          // dword offset of feature chunk

  float a0 = 0.f, a1 = 0.f, a2 = 0.f, a3 = 0.f;
  float a4 = 0.f, a5 = 0.f, a6 = 0.f, a7 = 0.f;
  int sc = cb[0];                             // iter 0 edge id
  int sn = cb[8];                             // iter 1 (guard-safe)
  uint4 u = *(const uint4*)(h32 + (sc << 5) + coff);
  for (int it = 1; it < iter; ++it) {
    int sf = cb[(it + 1) << 3];               // 2-ahead csr (guard-safe)
    uint4 r = *(const uint4*)(h32 + (sn << 5) + coff);
    acc_bf2(a0, a1, u.x); acc_bf2(a2, a3, u.y);
    acc_bf2(a4, a5, u.z); acc_bf2(a6, a7, u.w);
    u = r; sn = sf;
  }
  acc_bf2(a0, a1, u.x); acc_bf2(a2, a3, u.y);
  acc_bf2(a4, a5, u.z); acc_bf2(a6, a7, u.w);

  // reduce across the 8 edge-subgroups (lane bits 3,4,5)
#define RED3(a) a += __shfl_xor(a, 8); a += __shfl_xor(a, 16); a += __shfl_xor(a, 32);
  RED3(a0) RED3(a1) RED3(a2) RED3(a3) RED3(a4) RED3(a5) RED3(a6) RED3(a7)
#undef RED3

  float dn = dis[n];
  if (l < 8) {                                // lane l == chunk c: feats 8l..8l+7
    unsigned q0 = f2bf(a0 * dn) | (f2bf(a1 * dn) << 16);
    unsigned q1 = f2bf(a2 * dn) | (f2bf(a3 * dn) << 16);
    unsigned q2 = f2bf(a4 * dn) | (f2bf(a5 * dn) << 16);
    unsigned q3 = f2bf(a6 * dn) | (f2bf(a7 * dn) << 16);
    uint4* ap = (uint4*)(aggb + (size_t)n * 64 + (l << 3));
    *ap = make_uint4(q0, q1, q2, q3);
  }
}

// ---------------- final: MFMA GEMV  t = relu(aggb.W2 + b2); out = t.Wf + bf ----
// Wave = 16 nodes. mfma_f32_16x16x32_bf16: A lane = aggb[n0+(l&15)][(l>>4)*8+j]
// (direct ushort8 load, already bf16), B lane = bf16(W2[k][nt*16+(l&15)]),
// C layout (m89-verified): col = lane&15, row = (lane>>4)*4 + r.

__global__ void __launch_bounds__(256)
k_final(const unsigned short* __restrict__ aggb, const float* __restrict__ W2,
        const float* __restrict__ b2, const float* __restrict__ Wf,
        const float* __restrict__ bf, float* __restrict__ out) {
  int lane = threadIdx.x & 63;
  int wv = (blockIdx.x << 2) + (threadIdx.x >> 6);   // tile 0..KF_TILES-1
  if (wv >= KF_TILES) return;
  int n0 = wv << 4;
  int m = lane & 15;
  int kg = lane >> 4;                                // 0..3

  // B fragments: W2[k][n], k = kt*32 + kg*8 + j, n = nt*16 + m
  short8 bfr[2][4];
#pragma unroll
  for (int kt = 0; kt < 2; ++kt) {
#pragma unroll
    for (int nt = 0; nt < 4; ++nt) {
      short8 t;
#pragma unroll
      for (int j = 0; j < 8; ++j) {
        int k = kt * 32 + kg * 8 + j;
        t[j] = (short)f2bf(W2[k * 64 + nt * 16 + m]);
      }
      bfr[kt][nt] = t;
    }
  }
  // A fragments: row n0+m, k = kt*32 + kg*8 + j  (16-B aligned ushort8 loads)
  const unsigned short* ar = aggb + (size_t)(n0 + m) * 64 + kg * 8;
  short8 a0 = *(const short8*)(ar);
  short8 a1 = *(const short8*)(ar + 32);

  f32x4 z = {0.f, 0.f, 0.f, 0.f};
  f32x4 acc0 = z, acc1 = z, acc2 = z, acc3 = z;
  acc0 = __builtin_amdgcn_mfma_f32_16x16x32_bf16(a0, bfr[0][0], acc0, 0, 0, 0);
  acc1 = __builtin_amdgcn_mfma_f32_16x16x32_bf16(a0, bfr[0][1], acc1, 0, 0, 0);
  acc2 = __builtin_amdgcn_mfma_f32_16x16x32_bf16(a0, bfr[0][2], acc2, 0, 0, 0);
  acc3 = __builtin_amdgcn_mfma_f32_16x16x32_bf16(a0, bfr[0][3], acc3, 0, 0, 0);
  acc0 = __builtin_amdgcn_mfma_f32_16x16x32_bf16(a1, bfr[1][0], acc0, 0, 0, 0);
  acc1 = __builtin_amdgcn_mfma_f32_16x16x32_bf16(a1, bfr[1][1], acc1, 0, 0, 0);
  acc2 = __builtin_amdgcn_mfma_f32_16x16x32_bf16(a1, bfr[1][2], acc2, 0, 0, 0);
  acc3 = __builtin_amdgcn_mfma_f32_16x16x32_bf16(a1, bfr[1][3], acc3, 0, 0, 0);

  // epilogue: for each nt, col = nt*16+m; rows kg*4+r
  float p0[4] = {0.f, 0.f, 0.f, 0.f};
  float p1[4] = {0.f, 0.f, 0.f, 0.f};
#pragma unroll
  for (int nt = 0; nt < 4; ++nt) {
    int col = nt * 16 + m;
    float bb = b2[col];
    float w0 = Wf[col * 2 + 0];
    float w1 = Wf[col * 2 + 1];
    f32x4 av = (nt == 0) ? acc0 : (nt == 1) ? acc1 : (nt == 2) ? acc2 : acc3;
#pragma unroll
    for (int r = 0; r < 4; ++r) {
      float tv = fmaxf(av[r] + bb, 0.f);
      p0[r] = fmaf(tv, w0, p0[r]);
      p1[r] = fmaf(tv, w1, p1[r]);
    }
  }
  // reduce across the 16 columns (lane bits 0..3)
#pragma unroll
  for (int r = 0; r < 4; ++r) {
    p0[r] += __shfl_xor(p0[r], 1); p0[r] += __shfl_xor(p0[r], 2);
    p0[r] += __shfl_xor(p0[r], 4); p0[r] += __shfl_xor(p0[r], 8);
    p1[r] += __shfl_xor(p1[r], 1); p1[r] += __shfl_xor(p1[r], 2);
    p1[r] += __shfl_xor(p1[r], 4); p1[r] += __shfl_xor(p1[r], 8);
  }
  float bf0 = bf[0], bf1 = bf[1];
  int rowb = n0 + kg * 4;
  if (m == 0) *(float2*)(out + (rowb + 0) * 2) = make_float2(p0[0] + bf0, p1[0] + bf1);
  if (m == 1) *(float2*)(out + (rowb + 1) * 2) = make_float2(p0[1] + bf0, p1[1] + bf1);
  if (m == 2) *(float2*)(out + (rowb + 2) * 2) = make_float2(p0[2] + bf0, p1[2] + bf1);
  if (m == 3) *(float2*)(out + (rowb + 3) * 2) = make_float2(p0[3] + bf0, p1[3] + bf1);
}

// ---------------- launch ----------------

extern "C" void kernel_launch(void* const* d_in, const int* in_sizes, int n_in,
                              void* d_out, int out_size, void* d_ws, size_t ws_size,
                              hipStream_t stream) {
  const float* x  = (const float*)d_in[0];
  const int*   ei = (const int*)d_in[1];     // [2, E] row-major, int32
  const float* W1 = (const float*)d_in[2];
  const float* b1 = (const float*)d_in[3];
  const float* W2 = (const float*)d_in[4];
  const float* b2 = (const float*)d_in[5];
  const float* Wf = (const float*)d_in[6];
  const float* bf = (const float*)d_in[7];
  float* out = (float*)d_out;

  const int* srcv = ei;
  const int* dstv = ei + N_EDGES;

  char* p = (char*)d_ws;
  auto take = [&](size_t bytes) { char* r = p; p += (bytes + 255) & ~(size_t)255; return r; };
  int*          gcur = (int*)take((size_t)NBUCKET * GCS * 4);                   // 64-B strided counters
  unsigned int* eb   = (unsigned int*)take((size_t)NBUCKET * BCAP * 4 + 512);  // padded CSR
  int*          rs   = (int*)take((size_t)N_NODES * 4);
  int*          re   = (int*)take((size_t)N_NODES * 4);
  float*        dis  = (float*)take((size_t)N_NODES * 4);
  float4*       xd   = (float4*)take((size_t)(N_NODES + 1) * 16);               // + zero row
  __hip_bfloat16* h1s = (__hip_bfloat16*)take((size_t)(N_NODES + 1) * 64 * 2);  // + zero row
  unsigned short* aggb = (unsigned short*)take((size_t)N_NODES * 64 * 2);       // bf16, 12.8 MB

  (void)hipMemsetAsync(gcur, 0, (size_t)NBUCKET * GCS * 4, stream);
  k_pass1<<<NPB, 256, 0, stream>>>(srcv, dstv, gcur, eb);
  k_part2<<<NBUCKET, 512, 0, stream>>>(eb, gcur, rs, re, dis, (const float4*)x, xd);
  const int* csr = (const int*)eb;
  k_l1<<<((N_NODES + 1) * 4 + 255) / 256, 256, 0, stream>>>(xd, dis, rs, re, csr, W1, b1, (unsigned int*)h1s);
  k_agg<<<N_NODES / 4, 256, 0, stream>>>(h1s, dis, rs, re, csr, aggb);
  k_final<<<KF_BLOCKS, 256, 0, stream>>>(aggb, W2, b2, Wf, bf, out);
}

// Round 12
// 208.031 us; speedup vs baseline: 1.1920x; 1.0006x over previous
//
#include <hip/hip_runtime.h>
#include <hip/hip_bf16.h>

#define N_NODES 100000
#define N_EDGES 3200000
#define NB ((N_NODES + 255) / 256)   // 391
#define NBUCKET NB                   // coarse bucket = dst>>8
#define EPB 8192                     // edges per k_pass1 block
#define NPB ((N_EDGES + EPB - 1) / EPB)  // 391 blocks
#define BCAP 11264                   // per-bucket cap incl self+pad(8)+guard; mean ~9344, 20 sigma
#define KF_TILES (N_NODES / 16)      // 6250 MFMA tiles (16 nodes each), exact
#define KF_BLOCKS ((KF_TILES + 3) / 4)  // 1563 blocks of 4 waves
#define GCS 16                       // gcur stride (ints): 1 counter per 64-B line
#define NSH 8                        // src shards (src>>14) in part2's sort key
#define P2REG 17                     // part2 reg-cached items/thread (17*512=8704 >= cnt at +5.7 sigma)

typedef short short8 __attribute__((ext_vector_type(8)));
typedef float f32x4 __attribute__((ext_vector_type(4)));

// RNE float->bf16 bits (matches __float2bfloat16 for finite values)
__device__ inline unsigned f2bf(float f) {
  unsigned x = __float_as_uint(f);
  return (x + 0x7FFFu + ((x >> 16) & 1u)) >> 16;
}

// ---------------- pass 1: coarse partition with LDS-staged coalesced flush -----
// item: bits[16:0] = src, bits[24:17] = dst & 255 (bucket = dst>>8); per-item
// per-(block,bucket) position packed into bits[31:25] by the LDS-atomic hist.
// Items are bucket-sorted in LDS (sval/sbkt) via a hist prefix scan, then
// flushed in slot order -> consecutive slots within a bucket hit consecutive
// eb addresses (avg run ~21) => ~5x fewer global write transactions (R11: -4.6us).

__global__ void __launch_bounds__(256) k_pass1(const int* __restrict__ src,
                                               const int* __restrict__ dst,
                                               int* __restrict__ gcur,
                                               unsigned int* __restrict__ eb) {
  __shared__ int hist[NBUCKET];
  __shared__ int gbase[NBUCKET];
  __shared__ int lofs[NBUCKET];
  __shared__ int wsum[4];
  __shared__ unsigned int sval[EPB];
  __shared__ unsigned short sbkt[EPB];
  int tid = threadIdx.x;
  int lane = tid & 63, wid = tid >> 6;
  int base = blockIdx.x * EPB;
  int cnt = min(EPB, N_EDGES - base);   // multiple of 4
  int n4 = cnt >> 2;
  for (int i = tid; i < NBUCKET; i += 256) hist[i] = 0;
  __syncthreads();
  const int4* d4 = (const int4*)(dst + base);
  const int4* s4 = (const int4*)(src + base);
  unsigned mv[32];
  unsigned short mb[32];
#pragma unroll
  for (int k = 0; k < 8; ++k) {
    int i = tid + (k << 8);
    if (i < n4) {
      int4 dv = d4[i];
      int4 sv = s4[i];
      int b0 = dv.x >> 8, b1_ = dv.y >> 8, b2 = dv.z >> 8, b3 = dv.w >> 8;
      unsigned p0 = atomicAdd(&hist[b0], 1);
      unsigned p1 = atomicAdd(&hist[b1_], 1);
      unsigned p2 = atomicAdd(&hist[b2], 1);
      unsigned p3 = atomicAdd(&hist[b3], 1);
      mv[4 * k + 0] = (unsigned)sv.x | ((unsigned)(dv.x & 255) << 17) | (p0 << 25);
      mv[4 * k + 1] = (unsigned)sv.y | ((unsigned)(dv.y & 255) << 17) | (p1 << 25);
      mv[4 * k + 2] = (unsigned)sv.z | ((unsigned)(dv.z & 255) << 17) | (p2 << 25);
      mv[4 * k + 3] = (unsigned)sv.w | ((unsigned)(dv.w & 255) << 17) | (p3 << 25);
      mb[4 * k + 0] = (unsigned short)b0;
      mb[4 * k + 1] = (unsigned short)b1_;
      mb[4 * k + 2] = (unsigned short)b2;
      mb[4 * k + 3] = (unsigned short)b3;
    } else {
      mb[4 * k + 0] = 0xFFFF; mb[4 * k + 1] = 0xFFFF;
      mb[4 * k + 2] = 0xFFFF; mb[4 * k + 3] = 0xFFFF;
    }
  }
  __syncthreads();
  // claim global ranges (one atomic per (block,bucket))
  for (int b = tid; b < NBUCKET; b += 256) {
    int h = hist[b];
    gbase[b] = h ? atomicAdd(&gcur[b * GCS], h) : 0;
  }
  // prefix scan of hist (bucket-index order) -> lofs; 2 buckets per thread
  int b0i = 2 * tid, b1i = 2 * tid + 1;
  int h0 = (b0i < NBUCKET) ? hist[b0i] : 0;
  int h1 = (b1i < NBUCKET) ? hist[b1i] : 0;
  int v = h0 + h1;
#pragma unroll
  for (int off = 1; off < 64; off <<= 1) {
    int t = __shfl_up(v, off);
    if (lane >= off) v += t;
  }
  if (lane == 63) wsum[wid] = v;
  __syncthreads();
  int x = v;
#pragma unroll
  for (int w2 = 0; w2 < 3; ++w2)
    if (wid > w2) x += wsum[w2];
  int excl = x - (h0 + h1);
  if (b0i < NBUCKET) lofs[b0i] = excl;
  if (b1i < NBUCKET) lofs[b1i] = excl + h0;
  __syncthreads();
  // bucket-sorted LDS scatter: slot = lofs[b] + per-bucket position
#pragma unroll
  for (int k = 0; k < 32; ++k) {
    if (mb[k] != 0xFFFF) {
      int b = mb[k];
      unsigned m = mv[k];
      int slot = lofs[b] + (int)(m >> 25);
      sval[slot] = m & 0x01FFFFFFu;
      sbkt[slot] = (unsigned short)b;
    }
  }
  __syncthreads();
  // coalesced flush: consecutive slots in a bucket -> consecutive eb addresses
  for (int i = tid; i < cnt; i += 256) {
    int b = sbkt[i];
    int pos = gbase[b] + (i - lofs[b]);
    if (pos < BCAP) eb[(size_t)b * BCAP + pos] = sval[i];
  }
}

// ---------------- pass 2: per-bucket counting sort, SHARD-ORDERED runs ---------
// Sort key (node, src>>14): node n's run is [rs, re) with self edge first, then
// in-edges grouped by src shard. Pads to multiple of 8 + 16-entry guard.
// NEW: eb items are REGISTER-CACHED across the hist and scatter passes (same
// elements, same order) via a statically-unrolled P2REG-deep array -> the
// scatter pass has zero global reads (kills the second 12.8 MB eb pass).
// Dynamic tail loop re-reads global for the (statistically negligible)
// cnt > P2REG*512 overflow, preserving correctness at any cnt <= BCAP.

__global__ void __launch_bounds__(512) k_part2(unsigned int* __restrict__ eb,
                                               const int* __restrict__ gcur,
                                               int* __restrict__ rs, int* __restrict__ re,
                                               float* __restrict__ dis,
                                               const float4* __restrict__ x4,
                                               float4* __restrict__ xd) {
  __shared__ int hist2[256 * NSH];   // counts per (node, shard)
  __shared__ int sbase[256 * NSH];   // scatter cursors per (node, shard)
  __shared__ int wsum[4];
  __shared__ int tot;
  __shared__ unsigned int stage[BCAP];
  int b = blockIdx.x, tid = threadIdx.x;
  int lane = tid & 63, wid = tid >> 6;   // wid 0..7
  int n0 = b << 8;
  int cnt = gcur[b * GCS];
  int base = b * BCAP;
  for (int i = tid; i < 256 * NSH; i += 512) hist2[i] = 0;
  __syncthreads();
  unsigned it[P2REG];                // reg-cached items (static indexing only)
#pragma unroll
  for (int k = 0; k < P2REG; ++k) {
    int i = tid + (k << 9);
    if (i < cnt) {
      unsigned v2 = eb[base + i];
      it[k] = v2;
      atomicAdd(&hist2[((v2 >> 17) << 3) + ((v2 & 0x1FFFFu) >> 14)], 1);
    }
  }
  for (int i = tid + (P2REG << 9); i < cnt; i += 512) {   // overflow tail (rare)
    unsigned v2 = eb[base + i];
    atomicAdd(&hist2[((v2 >> 17) << 3) + ((v2 & 0x1FFFFu) >> 14)], 1);
  }
  __syncthreads();
  int n = n0 + tid;
  int deg = 0;
  int hs[NSH];
  if (tid < 256) {
#pragma unroll
    for (int s = 0; s < NSH; ++s) { hs[s] = hist2[(tid << 3) + s]; deg += hs[s]; }
  }
  int slots = (tid < 256 && n < N_NODES) ? ((deg + 1 + 7) & ~7) : 0;
  // inclusive scan of slots over the 256 node-threads: shfl within waves 0-3
  int v = slots;
  if (wid < 4) {
#pragma unroll
    for (int off = 1; off < 64; off <<= 1) {
      int t = __shfl_up(v, off);
      if (lane >= off) v += t;
    }
    if (lane == 63) wsum[wid] = v;
  }
  __syncthreads();
  int x = v;
  if (wid < 4) {
#pragma unroll
    for (int w2 = 0; w2 < 3; ++w2)
      if (wid > w2) x += wsum[w2];
  }
  int excl = x - slots;
  if (tid == 255) tot = x;
  if (tid < 256 && n < N_NODES) {
    rs[n]  = base + excl;
    re[n]  = base + excl + deg + 1;
    float dn = rsqrtf((float)(deg + 1));
    dis[n] = dn;
    float4 xv = x4[n];
    float4 w; w.x = xv.x * dn; w.y = xv.y * dn; w.z = xv.z * dn; w.w = xv.w * dn;
    xd[n] = w;
    stage[excl] = (unsigned)n;                    // self edge first
    for (int i = deg + 1; i < slots; ++i)
      stage[excl + i] = (unsigned)N_NODES;        // zero-row pads
    int o = excl + 1;                             // in-edges: shard-grouped
#pragma unroll
    for (int s = 0; s < NSH; ++s) { sbase[(tid << 3) + s] = o; o += hs[s]; }
  }
  if (b == 0 && tid == 0) xd[N_NODES] = make_float4(0.f, 0.f, 0.f, 0.f);
  __syncthreads();
#pragma unroll
  for (int k = 0; k < P2REG; ++k) {
    int i = tid + (k << 9);
    if (i < cnt) {
      unsigned v2 = it[k];
      unsigned srcv = v2 & 0x1FFFFu;
      int key = ((v2 >> 17) << 3) + (srcv >> 14);
      int lpos = atomicAdd(&sbase[key], 1);
      stage[lpos] = srcv;
    }
  }
  for (int i = tid + (P2REG << 9); i < cnt; i += 512) {   // overflow tail (rare)
    unsigned v2 = eb[base + i];
    unsigned srcv = v2 & 0x1FFFFu;
    int key = ((v2 >> 17) << 3) + (srcv >> 14);
    int lpos = atomicAdd(&sbase[key], 1);
    stage[lpos] = srcv;
  }
  __syncthreads();
  int total = tot;
  for (int i = tid; i < total; i += 512)
    eb[base + i] = stage[i];     // eb is now padded, shard-ordered CSR
  if (tid < 16) {                // guard pads for k_agg's prefetch over-read
    int gp = total + tid;
    if (gp < BCAP) eb[base + gp] = (unsigned)N_NODES;
  }
}

// ---------------- Layer 1 fused: aggregate xd + transform + bf16 store ----------
// 4 threads per node (p = gt&3). Thread p reads csr dwords e0+4t+p (slots are
// multiples of 8; pads hit xd's zero row), shfl_xor combine, then writes
// feature slice [16p, 16p+16) of h1s[n] = bf16(relu(b1 + agg·W1) * dis[n]).

__global__ void __launch_bounds__(256) k_l1(const float4* __restrict__ xd,
                                            const float* __restrict__ dis,
                                            const int* __restrict__ rs,
                                            const int* __restrict__ re,
                                            const int* __restrict__ csr,
                                            const float* __restrict__ W1,
                                            const float* __restrict__ b1,
                                            unsigned int* __restrict__ h1o) {
  int gt = blockIdx.x * 256 + threadIdx.x;
  int nid = gt >> 2, p = gt & 3;
  if (nid > N_NODES) return;
  if (nid == N_NODES) {                       // zero row (pad target for k_agg)
    uint4 z = make_uint4(0u, 0u, 0u, 0u);
    uint4* op = (uint4*)(h1o + nid * 32 + p * 8);
    op[0] = z; op[1] = z;
    return;
  }
  int e0 = rs[nid];
  int it4 = ((re[nid] - e0 + 7) & ~7) >> 2;   // dword quads per thread-pass
  const int* cp = csr + e0 + p;
  float ax = 0.f, ay = 0.f, az = 0.f, aw = 0.f;
#pragma unroll 4
  for (int t = 0; t < it4; ++t) {
    int s = cp[t << 2];
    float4 v = xd[s];
    ax += v.x; ay += v.y; az += v.z; aw += v.w;
  }
  ax += __shfl_xor(ax, 1); ax += __shfl_xor(ax, 2);
  ay += __shfl_xor(ay, 1); ay += __shfl_xor(ay, 2);
  az += __shfl_xor(az, 1); az += __shfl_xor(az, 2);
  aw += __shfl_xor(aw, 1); aw += __shfl_xor(aw, 2);
  float dn = dis[nid];
  ax *= dn; ay *= dn; az *= dn; aw *= dn;     // agg1[nid]
  int j0 = p << 4;
  unsigned ou[8];
#pragma unroll
  for (int j2 = 0; j2 < 8; ++j2) {
    int j = j0 + j2 * 2;
    float s0 = b1[j]     + ax * W1[j]     + ay * W1[64 + j]     + az * W1[128 + j]     + aw * W1[192 + j];
    float s1 = b1[j + 1] + ax * W1[j + 1] + ay * W1[64 + j + 1] + az * W1[128 + j + 1] + aw * W1[192 + j + 1];
    unsigned u0 = f2bf(fmaxf(s0, 0.f) * dn);
    unsigned u1 = f2bf(fmaxf(s1, 0.f) * dn);
    ou[j2] = u0 | (u1 << 16);
  }
  uint4* op = (uint4*)(h1o + nid * 32 + p * 8);
  op[0] = make_uint4(ou[0], ou[1], ou[2], ou[3]);
  op[1] = make_uint4(ou[4], ou[5], ou[6], ou[7]);
}

// ---------------- Layer-2 aggregation: 2-deep pipelined gather (r1 proven) ----
// Wave per node. Lane l: g = l>>3 (edge subgroup 0..7), c = l&7 (uint4 chunk).
// At the random-128B-request L3-path roofline (R4 depth-test + R10 FETCH-
// invariance both confirm; ~3.2 TB/s effective on this path).

__device__ inline void acc_bf2(float& a0, float& a1, unsigned u) {
  a0 += __uint_as_float(u << 16);
  a1 += __uint_as_float(u & 0xffff0000u);
}

__global__ void __launch_bounds__(256)
k_agg(const __hip_bfloat16* __restrict__ h1s, const float* __restrict__ dis,
      const int* __restrict__ rs, const int* __restrict__ re,
      const int* __restrict__ csr, unsigned short* __restrict__ aggb) {
  int l = threadIdx.x & 63;
  int w = threadIdx.x >> 6;
  int n = blockIdx.x * 4 + w;   // grid = N/4 exactly
  int g = l >> 3;
  int c = l & 7;

  const unsigned int* h32 = (const unsigned int*)h1s;
  int e0 = rs[n];
  int iter = (re[n] - e0 + 7) >> 3;           // padded 8-blocks, >= 1
  const int* cb = csr + e0 + g;
  int coff = c << 2;                          // dword offset of feature chunk

  float a0 = 0.f, a1 = 0.f, a2 = 0.f, a3 = 0.f;
  float a4 = 0.f, a5 = 0.f, a6 = 0.f, a7 = 0.f;
  int sc = cb[0];                             // iter 0 edge id
  int sn = cb[8];                             // iter 1 (guard-safe)
  uint4 u = *(const uint4*)(h32 + (sc << 5) + coff);
  for (int it = 1; it < iter; ++it) {
    int sf = cb[(it + 1) << 3];               // 2-ahead csr (guard-safe)
    uint4 r = *(const uint4*)(h32 + (sn << 5) + coff);
    acc_bf2(a0, a1, u.x); acc_bf2(a2, a3, u.y);
    acc_bf2(a4, a5, u.z); acc_bf2(a6, a7, u.w);
    u = r; sn = sf;
  }
  acc_bf2(a0, a1, u.x); acc_bf2(a2, a3, u.y);
  acc_bf2(a4, a5, u.z); acc_bf2(a6, a7, u.w);

  // reduce across the 8 edge-subgroups (lane bits 3,4,5)
#define RED3(a) a += __shfl_xor(a, 8); a += __shfl_xor(a, 16); a += __shfl_xor(a, 32);
  RED3(a0) RED3(a1) RED3(a2) RED3(a3) RED3(a4) RED3(a5) RED3(a6) RED3(a7)
#undef RED3

  float dn = dis[n];
  if (l < 8) {                                // lane l == chunk c: feats 8l..8l+7
    unsigned q0 = f2bf(a0 * dn) | (f2bf(a1 * dn) << 16);
    unsigned q1 = f2bf(a2 * dn) | (f2bf(a3 * dn) << 16);
    unsigned q2 = f2bf(a4 * dn) | (f2bf(a5 * dn) << 16);
    unsigned q3 = f2bf(a6 * dn) | (f2bf(a7 * dn) << 16);
    uint4* ap = (uint4*)(aggb + (size_t)n * 64 + (l << 3));
    *ap = make_uint4(q0, q1, q2, q3);
  }
}

// ---------------- final: MFMA GEMV  t = relu(aggb.W2 + b2); out = t.Wf + bf ----
// Wave = 16 nodes. mfma_f32_16x16x32_bf16: A lane = aggb[n0+(l&15)][(l>>4)*8+j]
// (direct ushort8 load, already bf16), B lane = bf16(W2[k][nt*16+(l&15)]),
// C layout (m89-verified): col = lane&15, row = (lane>>4)*4 + r.

__global__ void __launch_bounds__(256)
k_final(const unsigned short* __restrict__ aggb, const float* __restrict__ W2,
        const float* __restrict__ b2, const float* __restrict__ Wf,
        const float* __restrict__ bf, float* __restrict__ out) {
  int lane = threadIdx.x & 63;
  int wv = (blockIdx.x << 2) + (threadIdx.x >> 6);   // tile 0..KF_TILES-1
  if (wv >= KF_TILES) return;
  int n0 = wv << 4;
  int m = lane & 15;
  int kg = lane >> 4;                                // 0..3

  // B fragments: W2[k][n], k = kt*32 + kg*8 + j, n = nt*16 + m
  short8 bfr[2][4];
#pragma unroll
  for (int kt = 0; kt < 2; ++kt) {
#pragma unroll
    for (int nt = 0; nt < 4; ++nt) {
      short8 t;
#pragma unroll
      for (int j = 0; j < 8; ++j) {
        int k = kt * 32 + kg * 8 + j;
        t[j] = (short)f2bf(W2[k * 64 + nt * 16 + m]);
      }
      bfr[kt][nt] = t;
    }
  }
  // A fragments: row n0+m, k = kt*32 + kg*8 + j  (16-B aligned ushort8 loads)
  const unsigned short* ar = aggb + (size_t)(n0 + m) * 64 + kg * 8;
  short8 a0 = *(const short8*)(ar);
  short8 a1 = *(const short8*)(ar + 32);

  f32x4 z = {0.f, 0.f, 0.f, 0.f};
  f32x4 acc0 = z, acc1 = z, acc2 = z, acc3 = z;
  acc0 = __builtin_amdgcn_mfma_f32_16x16x32_bf16(a0, bfr[0][0], acc0, 0, 0, 0);
  acc1 = __builtin_amdgcn_mfma_f32_16x16x32_bf16(a0, bfr[0][1], acc1, 0, 0, 0);
  acc2 = __builtin_amdgcn_mfma_f32_16x16x32_bf16(a0, bfr[0][2], acc2, 0, 0, 0);
  acc3 = __builtin_amdgcn_mfma_f32_16x16x32_bf16(a0, bfr[0][3], acc3, 0, 0, 0);
  acc0 = __builtin_amdgcn_mfma_f32_16x16x32_bf16(a1, bfr[1][0], acc0, 0, 0, 0);
  acc1 = __builtin_amdgcn_mfma_f32_16x16x32_bf16(a1, bfr[1][1], acc1, 0, 0, 0);
  acc2 = __builtin_amdgcn_mfma_f32_16x16x32_bf16(a1, bfr[1][2], acc2, 0, 0, 0);
  acc3 = __builtin_amdgcn_mfma_f32_16x16x32_bf16(a1, bfr[1][3], acc3, 0, 0, 0);

  // epilogue: for each nt, col = nt*16+m; rows kg*4+r
  float p0[4] = {0.f, 0.f, 0.f, 0.f};
  float p1[4] = {0.f, 0.f, 0.f, 0.f};
#pragma unroll
  for (int nt = 0; nt < 4; ++nt) {
    int col = nt * 16 + m;
    float bb = b2[col];
    float w0 = Wf[col * 2 + 0];
    float w1 = Wf[col * 2 + 1];
    f32x4 av = (nt == 0) ? acc0 : (nt == 1) ? acc1 : (nt == 2) ? acc2 : acc3;
#pragma unroll
    for (int r = 0; r < 4; ++r) {
      float tv = fmaxf(av[r] + bb, 0.f);
      p0[r] = fmaf(tv, w0, p0[r]);
      p1[r] = fmaf(tv, w1, p1[r]);
    }
  }
  // reduce across the 16 columns (lane bits 0..3)
#pragma unroll
  for (int r = 0; r < 4; ++r) {
    p0[r] += __shfl_xor(p0[r], 1); p0[r] += __shfl_xor(p0[r], 2);
    p0[r] += __shfl_xor(p0[r], 4); p0[r] += __shfl_xor(p0[r], 8);
    p1[r] += __shfl_xor(p1[r], 1); p1[r] += __shfl_xor(p1[r], 2);
    p1[r] += __shfl_xor(p1[r], 4); p1[r] += __shfl_xor(p1[r], 8);
  }
  float bf0 = bf[0], bf1 = bf[1];
  int rowb = n0 + kg * 4;
  if (m == 0) *(float2*)(out + (rowb + 0) * 2) = make_float2(p0[0] + bf0, p1[0] + bf1);
  if (m == 1) *(float2*)(out + (rowb + 1) * 2) = make_float2(p0[1] + bf0, p1[1] + bf1);
  if (m == 2) *(float2*)(out + (rowb + 2) * 2) = make_float2(p0[2] + bf0, p1[2] + bf1);
  if (m == 3) *(float2*)(out + (rowb + 3) * 2) = make_float2(p0[3] + bf0, p1[3] + bf1);
}

// ---------------- launch ----------------

extern "C" void kernel_launch(void* const* d_in, const int* in_sizes, int n_in,
                              void* d_out, int out_size, void* d_ws, size_t ws_size,
                              hipStream_t stream) {
  const float* x  = (const float*)d_in[0];
  const int*   ei = (const int*)d_in[1];     // [2, E] row-major, int32
  const float* W1 = (const float*)d_in[2];
  const float* b1 = (const float*)d_in[3];
  const float* W2 = (const float*)d_in[4];
  const float* b2 = (const float*)d_in[5];
  const float* Wf = (const float*)d_in[6];
  const float* bf = (const float*)d_in[7];
  float* out = (float*)d_out;

  const int* srcv = ei;
  const int* dstv = ei + N_EDGES;

  char* p = (char*)d_ws;
  auto take = [&](size_t bytes) { char* r = p; p += (bytes + 255) & ~(size_t)255; return r; };
  int*          gcur = (int*)take((size_t)NBUCKET * GCS * 4);                   // 64-B strided counters
  unsigned int* eb   = (unsigned int*)take((size_t)NBUCKET * BCAP * 4 + 512);  // padded CSR
  int*          rs   = (int*)take((size_t)N_NODES * 4);
  int*          re   = (int*)take((size_t)N_NODES * 4);
  float*        dis  = (float*)take((size_t)N_NODES * 4);
  float4*       xd   = (float4*)take((size_t)(N_NODES + 1) * 16);               // + zero row
  __hip_bfloat16* h1s = (__hip_bfloat16*)take((size_t)(N_NODES + 1) * 64 * 2);  // + zero row
  unsigned short* aggb = (unsigned short*)take((size_t)N_NODES * 64 * 2);       // bf16, 12.8 MB

  (void)hipMemsetAsync(gcur, 0, (size_t)NBUCKET * GCS * 4, stream);
  k_pass1<<<NPB, 256, 0, stream>>>(srcv, dstv, gcur, eb);
  k_part2<<<NBUCKET, 512, 0, stream>>>(eb, gcur, rs, re, dis, (const float4*)x, xd);
  const int* csr = (const int*)eb;
  k_l1<<<((N_NODES + 1) * 4 + 255) / 256, 256, 0, stream>>>(xd, dis, rs, re, csr, W1, b1, (unsigned int*)h1s);
  k_agg<<<N_NODES / 4, 256, 0, stream>>>(h1s, dis, rs, re, csr, aggb);
  k_final<<<KF_BLOCKS, 256, 0, stream>>>(aggb, W2, b2, Wf, bf, out);
}